// Round 8
// baseline (167.741 us; speedup 1.0000x reference)
//
#include <hip/hip_runtime.h>
#include <math.h>

#define TQ   32768
#define HWSZ 16384
#define CC   64
#define HH   128
#define WW   128
#define C3   192
#define C4   256
#define KS   7

typedef _Float16 half2v __attribute__((ext_vector_type(2)));
typedef _Float16 half4v __attribute__((ext_vector_type(4)));
typedef _Float16 half8v __attribute__((ext_vector_type(8)));
typedef float    f32x4  __attribute__((ext_vector_type(4)));

#define MFMA16(a, b, c) __builtin_amdgcn_mfma_f32_16x16x32_f16((a), (b), (c), 0, 0, 0)

// ============ K1: LN1 + QKV GEMM, all 192 cols per block. grid 256 ============
__global__ __launch_bounds__(256) void k_qkvln(const float* __restrict__ x,
        const float* __restrict__ lnw, const float* __restrict__ lnb,
        const float* __restrict__ qw, const float* __restrict__ qb,
        _Float16* __restrict__ qkv16) {
    __shared__ union {
        struct { __align__(16) _Float16 A[128 * 72]; __align__(16) _Float16 B[192 * 72]; } st;
        __align__(16) _Float16 outb[128 * 200];
    } u;
    __shared__ float ps1[256], ps2[256], m_s[128], r_s[128];
    __shared__ float w_s[64], b_s[64], bias_s[192];
    int tid = threadIdx.x;
    int t0 = blockIdx.x * 128;
    if (tid < 64) { w_s[tid] = lnw[tid]; b_s[tid] = lnb[tid]; }
    if (tid < 192) bias_s[tid] = qb[tid];
    // LN stats in registers: thread = (cq = tid>>7, tok = tid&127), 32 channels each
    int tok = tid & 127, cq = tid >> 7;
    int t = t0 + tok;
    int n = t >> 14, hw = t & (HWSZ - 1);
    const float* xr = x + ((size_t)n << 20) + hw;
    float v[32];
    float s = 0.f, s2 = 0.f;
#pragma unroll
    for (int e = 0; e < 32; ++e) {
        float f = xr[(cq * 32 + e) * HWSZ];
        v[e] = f; s += f; s2 += f * f;
    }
    ps1[tid] = s; ps2[tid] = s2;
    // stage all 192 weight rows meanwhile
    for (int i = tid; i < 3072; i += 256) {
        int jj = i >> 4, seg = i & 15;
        float4 v4 = *(const float4*)&qw[(size_t)jj * 64 + seg * 4];
        half4v h4 = { (_Float16)v4.x, (_Float16)v4.y, (_Float16)v4.z, (_Float16)v4.w };
        *(half4v*)&u.st.B[jj * 72 + seg * 4] = h4;
    }
    __syncthreads();
    if (tid < 128) {
        float ss = ps1[tid] + ps1[tid + 128];
        float qq = ps2[tid] + ps2[tid + 128];
        float m = ss * (1.f / 64.f);
        float var = qq * (1.f / 64.f) - m * m;
        m_s[tid] = m; r_s[tid] = rsqrtf(var + 1e-5f);
    }
    __syncthreads();
    {
        float m = m_s[tok], r = r_s[tok];
#pragma unroll
        for (int u8 = 0; u8 < 4; ++u8) {
            half8v o;
#pragma unroll
            for (int e = 0; e < 8; ++e) {
                int c = cq * 32 + u8 * 8 + e;
                o[e] = (_Float16)((v[u8 * 8 + e] - m) * r * w_s[c] + b_s[c]);
            }
            *(half8v*)&u.st.A[tok * 72 + cq * 32 + u8 * 8] = o;
        }
    }
    __syncthreads();
    // GEMM: waves 2x2, wave tile 64t x 96j
    int lane = tid & 63, wv = tid >> 6;
    int quad = lane >> 4, l16 = lane & 15;
    int mt0 = (wv & 1) * 64, nt0 = (wv >> 1) * 96;
    f32x4 acc[4][6];
#pragma unroll
    for (int mf = 0; mf < 4; ++mf)
#pragma unroll
        for (int nf = 0; nf < 6; ++nf) acc[mf][nf] = (f32x4){0.f, 0.f, 0.f, 0.f};
#pragma unroll
    for (int ks = 0; ks < 64; ks += 32) {
        half8v a[4], bfr[6];
#pragma unroll
        for (int mf = 0; mf < 4; ++mf)
            a[mf] = *(const half8v*)&u.st.A[(mt0 + mf * 16 + l16) * 72 + ks + quad * 8];
#pragma unroll
        for (int nf = 0; nf < 6; ++nf)
            bfr[nf] = *(const half8v*)&u.st.B[(nt0 + nf * 16 + l16) * 72 + ks + quad * 8];
#pragma unroll
        for (int mf = 0; mf < 4; ++mf)
#pragma unroll
            for (int nf = 0; nf < 6; ++nf) acc[mf][nf] = MFMA16(a[mf], bfr[nf], acc[mf][nf]);
    }
    __syncthreads();   // all waves done reading A/B before outb overwrite
    const float qscale = 0.17677669529663687f;
#pragma unroll
    for (int mf = 0; mf < 4; ++mf)
#pragma unroll
        for (int nf = 0; nf < 6; ++nf) {
            int j = nt0 + nf * 16 + l16;
            float bias = bias_s[j];
            float sc = (j < 64) ? qscale : 1.f;
#pragma unroll
            for (int r = 0; r < 4; ++r) {
                int tl = mt0 + mf * 16 + quad * 4 + r;
                u.outb[tl * 200 + j] = (_Float16)((acc[mf][nf][r] + bias) * sc);
            }
        }
    __syncthreads();
    // coalesced stores: 24 half8 chunks per token
    for (int i = tid; i < 4096; i += 256) {
        int tk = i >> 5, rem = i & 31;
        if (rem < 24)
            *(half8v*)&qkv16[(size_t)(t0 + tk) * C3 + rem * 8] =
                *(const half8v*)&u.outb[tk * 200 + rem * 8];
    }
}

// ============ K2: neighborhood attention, one head per block (unchanged) ============
#define KST 34
__global__ __launch_bounds__(256) void k_attn(const _Float16* __restrict__ qkv16,
        const float* __restrict__ rpb, _Float16* __restrict__ attn16) {
    __shared__ __align__(16) _Float16 k_s[196 * KST];
    __shared__ __align__(16) _Float16 v_s[196 * KST];
    __shared__ __align__(16) _Float16 q_s[64 * KST];
    __shared__ _Float16 s_s[64 * 50];
    __shared__ float rpb_s[169];
    int tid = threadIdx.x;
    int bx = blockIdx.x;
    int n = bx >> 9, z = (bx >> 8) & 1;
    int th = (bx >> 4) & 15, tw = bx & 15;
    int h0 = th * 8, w0 = tw * 8;
    int wr0 = min(max(h0 - 3, 0), HH - 14);
    int ww0 = min(max(w0 - 3, 0), WW - 14);
    int tbase = n << 14;
    if (tid < 169) rpb_s[tid] = rpb[z * 169 + tid];
    for (int i = tid; i < 784; i += 256) {
        int tok = i >> 2, uu = i & 3;
        int wi = (tok * 586) >> 13;
        int wj = tok - wi * 14;
        const _Float16* src = qkv16 +
            (size_t)(tbase + (wr0 + wi) * WW + ww0 + wj) * C3 + 64 + z * 32 + uu * 8;
        *(half8v*)&k_s[tok * KST + uu * 8] = *(const half8v*)src;
        *(half8v*)&v_s[tok * KST + uu * 8] = *(const half8v*)(src + 64);
    }
    {
        int q = tid >> 2, uu = tid & 3;
        int qg = tbase + (h0 + (q >> 3)) * WW + (w0 + (q & 7));
        *(half8v*)&q_s[q * KST + uu * 8] = *(const half8v*)&qkv16[(size_t)qg * C3 + z * 32 + uu * 8];
    }
    __syncthreads();
    int q = tid & 63;
    int qy = q >> 3, qx = q & 7;
    int h = h0 + qy, wc = w0 + qx;
    int sh = min(max(h - 3, 0), HH - KS);
    int sw = min(max(wc - 3, 0), WW - KS);
    int oh = sh - wr0, ow = sw - ww0;
    int dhp = h - sh + 6, dwp = wc - sw + 6;
    {
        int nbq = tid >> 6;
        const half8v* qp = (const half8v*)&q_s[q * KST];
        half8v q0 = qp[0], q1 = qp[1], q2 = qp[2], q3 = qp[3];
        int i7 = 0, j7 = nbq;
        int cnt = (nbq == 0) ? 13 : 12;
        int nb = nbq;
        for (int it = 0; it < cnt; ++it) {
            int tok = (oh + i7) * 14 + (ow + j7);
            const half8v* kp = (const half8v*)&k_s[tok * KST];
            half2v a2 = { (_Float16)0.f, (_Float16)0.f };
            a2 += (half2v){kp[0].s0, kp[0].s1} * (half2v){q0.s0, q0.s1};
            a2 += (half2v){kp[0].s2, kp[0].s3} * (half2v){q0.s2, q0.s3};
            a2 += (half2v){kp[0].s4, kp[0].s5} * (half2v){q0.s4, q0.s5};
            a2 += (half2v){kp[0].s6, kp[0].s7} * (half2v){q0.s6, q0.s7};
            a2 += (half2v){kp[1].s0, kp[1].s1} * (half2v){q1.s0, q1.s1};
            a2 += (half2v){kp[1].s2, kp[1].s3} * (half2v){q1.s2, q1.s3};
            a2 += (half2v){kp[1].s4, kp[1].s5} * (half2v){q1.s4, q1.s5};
            a2 += (half2v){kp[1].s6, kp[1].s7} * (half2v){q1.s6, q1.s7};
            a2 += (half2v){kp[2].s0, kp[2].s1} * (half2v){q2.s0, q2.s1};
            a2 += (half2v){kp[2].s2, kp[2].s3} * (half2v){q2.s2, q2.s3};
            a2 += (half2v){kp[2].s4, kp[2].s5} * (half2v){q2.s4, q2.s5};
            a2 += (half2v){kp[2].s6, kp[2].s7} * (half2v){q2.s6, q2.s7};
            a2 += (half2v){kp[3].s0, kp[3].s1} * (half2v){q3.s0, q3.s1};
            a2 += (half2v){kp[3].s2, kp[3].s3} * (half2v){q3.s2, q3.s3};
            a2 += (half2v){kp[3].s4, kp[3].s5} * (half2v){q3.s4, q3.s5};
            a2 += (half2v){kp[3].s6, kp[3].s7} * (half2v){q3.s6, q3.s7};
            float sc = (float)a2.x + (float)a2.y + rpb_s[(dhp - i7) * 13 + (dwp - j7)];
            s_s[q * 50 + nb] = (_Float16)sc;
            nb += 4;
            j7 += 4; if (j7 >= 7) { j7 -= 7; ++i7; }
        }
    }
    __syncthreads();
    if (tid < 64) {
        _Float16* sp = &s_s[tid * 50];
        float mx = -1e30f;
        for (int i = 0; i < 49; ++i) mx = fmaxf(mx, (float)sp[i]);
        float sum = 0.f;
        for (int i = 0; i < 49; ++i) {
            float e = __expf((float)sp[i] - mx);
            sum += e;
            sp[i] = (_Float16)e;
        }
        float inv = 1.f / sum;
        for (int i = 0; i < 49; ++i) sp[i] = (_Float16)((float)sp[i] * inv);
    }
    __syncthreads();
    {
        int c8 = tid >> 6;
        const _Float16* pp = &s_s[q * 50];
        half2v acc[4];
#pragma unroll
        for (int jv = 0; jv < 4; ++jv) acc[jv] = (half2v){ (_Float16)0.f, (_Float16)0.f };
        int i7 = 0, j7 = 0;
        for (int nb = 0; nb < 49; ++nb) {
            int tok = (oh + i7) * 14 + (ow + j7);
            _Float16 p = pp[nb];
            half2v p2 = { p, p };
            half8v vv = *(const half8v*)&v_s[tok * KST + c8 * 8];
            acc[0] += (half2v){vv.s0, vv.s1} * p2;
            acc[1] += (half2v){vv.s2, vv.s3} * p2;
            acc[2] += (half2v){vv.s4, vv.s5} * p2;
            acc[3] += (half2v){vv.s6, vv.s7} * p2;
            ++j7; if (j7 == 7) { j7 = 0; ++i7; }
        }
        int qg = tbase + h * WW + wc;
        half8v o = { acc[0].x, acc[0].y, acc[1].x, acc[1].y,
                     acc[2].x, acc[2].y, acc[3].x, acc[3].y };
        *(half8v*)&attn16[(size_t)qg * CC + z * 32 + c8 * 8] = o;
    }
}

// ============ K3: proj + residual + LN2 + FC1 + GELU fused. grid 256 (128 tokens) ============
__global__ __launch_bounds__(256) void k_projfc1(const _Float16* __restrict__ ain,
        const float* __restrict__ pw, const float* __restrict__ pb,
        const float* __restrict__ x,
        const float* __restrict__ ln2w, const float* __restrict__ ln2b,
        const float* __restrict__ f1w, const float* __restrict__ f1b,
        _Float16* __restrict__ x2_16, _Float16* __restrict__ hbuf16) {
    __shared__ __align__(16) _Float16 regA[128 * 72];   // proj A -> fc1 A (normalized)
    __shared__ __align__(16) _Float16 regB[128 * 72];   // proj B / fc1 B-half
    __shared__ __align__(16) char regX[34816];          // x2t f32[128*67] / out f16[128*136]
    __shared__ float ps1[256], ps2[256], m_s[128], r_s[128];
    __shared__ float w_s[64], b_s[64], pbias[64], f1bias[256];
    float* x2t = (float*)regX;
    _Float16* outt = (_Float16*)regX;
    int tid = threadIdx.x;
    int t0 = blockIdx.x * 128;
    int n = t0 >> 14, hw0 = t0 & (HWSZ - 1);
    int lane = tid & 63, wv = tid >> 6;
    int quad = lane >> 4, l16 = lane & 15;
    if (tid < 64) { w_s[tid] = ln2w[tid]; b_s[tid] = ln2b[tid]; pbias[tid] = pb[tid]; }
    f1bias[tid] = f1b[tid];
    for (int i = tid; i < 1024; i += 256) {
        int tok = i >> 3, u8 = i & 7;
        *(half8v*)&regA[tok * 72 + u8 * 8] = *(const half8v*)&ain[(size_t)(t0 + tok) * 64 + u8 * 8];
    }
    for (int i = tid; i < 1024; i += 256) {
        int jj = i >> 4, seg = i & 15;
        float4 v4 = *(const float4*)&pw[(size_t)jj * 64 + seg * 4];
        half4v h4 = { (_Float16)v4.x, (_Float16)v4.y, (_Float16)v4.z, (_Float16)v4.w };
        *(half4v*)&regB[jj * 72 + seg * 4] = h4;
    }
    __syncthreads();
    // --- proj GEMM: 4 waves x (32t x 64j) ---
    {
        int mt0 = wv * 32;
        f32x4 acc[2][4];
#pragma unroll
        for (int mf = 0; mf < 2; ++mf)
#pragma unroll
            for (int nf = 0; nf < 4; ++nf) acc[mf][nf] = (f32x4){0.f, 0.f, 0.f, 0.f};
#pragma unroll
        for (int ks = 0; ks < 64; ks += 32) {
            half8v a[2], bfr[4];
#pragma unroll
            for (int mf = 0; mf < 2; ++mf)
                a[mf] = *(const half8v*)&regA[(mt0 + mf * 16 + l16) * 72 + ks + quad * 8];
#pragma unroll
            for (int nf = 0; nf < 4; ++nf)
                bfr[nf] = *(const half8v*)&regB[(nf * 16 + l16) * 72 + ks + quad * 8];
#pragma unroll
            for (int mf = 0; mf < 2; ++mf)
#pragma unroll
                for (int nf = 0; nf < 4; ++nf) acc[mf][nf] = MFMA16(a[mf], bfr[nf], acc[mf][nf]);
        }
        // epilogue -> x2t (own cells only, no cross-wave hazard)
#pragma unroll
        for (int mf = 0; mf < 2; ++mf)
#pragma unroll
            for (int nf = 0; nf < 4; ++nf) {
                int j = nf * 16 + l16;
                float bias = pbias[j];
                int hwl = hw0 + mt0 + mf * 16 + quad * 4;
                float4 rx = *(const float4*)&x[((size_t)(n * CC + j) << 14) + hwl];
#pragma unroll
                for (int r = 0; r < 4; ++r) {
                    int tl = mt0 + mf * 16 + quad * 4 + r;
                    x2t[tl * 67 + j] = acc[mf][nf][r] + bias + ((const float*)&rx)[r];
                }
            }
    }
    __syncthreads();
    // --- LN2 stats ---
    int tok = tid & 127, cq = tid >> 7;
    {
        float s = 0.f, s2 = 0.f;
#pragma unroll
        for (int e = 0; e < 32; ++e) {
            float f = x2t[tok * 67 + cq * 32 + e];
            s += f; s2 += f * f;
        }
        ps1[tid] = s; ps2[tid] = s2;
    }
    __syncthreads();
    if (tid < 128) {
        float ss = ps1[tid] + ps1[tid + 128];
        float qq = ps2[tid] + ps2[tid + 128];
        float m = ss * (1.f / 64.f);
        float var = qq * (1.f / 64.f) - m * m;
        m_s[tid] = m; r_s[tid] = rsqrtf(var + 1e-5f);
    }
    __syncthreads();
    // --- write x2_16 global; normalized -> regA (fc1 A operand) ---
    {
        float m = m_s[tok], r = r_s[tok];
#pragma unroll
        for (int u8 = 0; u8 < 4; ++u8) {
            half8v hv, nv;
#pragma unroll
            for (int e = 0; e < 8; ++e) {
                int c = cq * 32 + u8 * 8 + e;
                float f = x2t[tok * 67 + c];
                hv[e] = (_Float16)f;
                nv[e] = (_Float16)((f - m) * r * w_s[c] + b_s[c]);
            }
            *(half8v*)&x2_16[(size_t)(t0 + tok) * 64 + cq * 32 + u8 * 8] = hv;
            *(half8v*)&regA[tok * 72 + cq * 32 + u8 * 8] = nv;
        }
    }
    // --- FC1: two sequential 128-j halves ---
    for (int jh = 0; jh < 2; ++jh) {
        __syncthreads();
        for (int i = tid; i < 2048; i += 256) {
            int jj = i >> 4, seg = i & 15;
            float4 v4 = *(const float4*)&f1w[(size_t)(jh * 128 + jj) * 64 + seg * 4];
            half4v h4 = { (_Float16)v4.x, (_Float16)v4.y, (_Float16)v4.z, (_Float16)v4.w };
            *(half4v*)&regB[jj * 72 + seg * 4] = h4;
        }
        __syncthreads();
        int mt0 = (wv & 1) * 64, nt0 = (wv >> 1) * 64;
        f32x4 acc[4][4];
#pragma unroll
        for (int mf = 0; mf < 4; ++mf)
#pragma unroll
            for (int nf = 0; nf < 4; ++nf) acc[mf][nf] = (f32x4){0.f, 0.f, 0.f, 0.f};
#pragma unroll
        for (int ks = 0; ks < 64; ks += 32) {
            half8v a[4], bfr[4];
#pragma unroll
            for (int mf = 0; mf < 4; ++mf)
                a[mf] = *(const half8v*)&regA[(mt0 + mf * 16 + l16) * 72 + ks + quad * 8];
#pragma unroll
            for (int nf = 0; nf < 4; ++nf)
                bfr[nf] = *(const half8v*)&regB[(nt0 + nf * 16 + l16) * 72 + ks + quad * 8];
#pragma unroll
            for (int mf = 0; mf < 4; ++mf)
#pragma unroll
                for (int nf = 0; nf < 4; ++nf) acc[mf][nf] = MFMA16(a[mf], bfr[nf], acc[mf][nf]);
        }
        __syncthreads();   // x2t reads done in prior phases; outt overwrite safe; also B restage fence
#pragma unroll
        for (int mf = 0; mf < 4; ++mf)
#pragma unroll
            for (int nf = 0; nf < 4; ++nf) {
                int jl = nt0 + nf * 16 + l16;
                float bias = f1bias[jh * 128 + jl];
#pragma unroll
                for (int r = 0; r < 4; ++r) {
                    int tl = mt0 + mf * 16 + quad * 4 + r;
                    float vv = acc[mf][nf][r] + bias;
                    float g = 0.5f * vv * (1.f + erff(vv * 0.70710678118654752f));
                    outt[tl * 136 + jl] = (_Float16)g;
                }
            }
        __syncthreads();
        for (int i = tid; i < 2048; i += 256) {
            int tk = i >> 4, jc = i & 15;
            *(half8v*)&hbuf16[(size_t)(t0 + tk) * C4 + jh * 128 + jc * 8] =
                *(const half8v*)&outt[tk * 136 + jc * 8];
        }
    }
}

// ============ K4: FC2 GEMM (K=256) + residual + NCHW f32 out (unchanged) ============
__global__ __launch_bounds__(256) void k_fc2(const _Float16* __restrict__ hbuf16,
        const float* __restrict__ fw, const float* __restrict__ fb,
        const _Float16* __restrict__ x2_16, float* __restrict__ out) {
    __shared__ union {
        struct { __align__(16) _Float16 A[128 * 72]; __align__(16) _Float16 B[64 * 72]; } st;
        float tr[64 * 132];
    } u;
    __shared__ float fb_s[64];
    int tid = threadIdx.x;
    int t0 = blockIdx.x * 128;
    int lane = tid & 63, wv = tid >> 6;
    int quad = lane >> 4, l16 = lane & 15;
    int mt0 = wv * 32;
    if (tid < 64) fb_s[tid] = fb[tid];
    f32x4 acc[2][4];
#pragma unroll
    for (int mf = 0; mf < 2; ++mf)
#pragma unroll
        for (int nf = 0; nf < 4; ++nf) acc[mf][nf] = (f32x4){0.f, 0.f, 0.f, 0.f};
    for (int kp = 0; kp < 4; ++kp) {
        if (kp) __syncthreads();
        for (int i = tid; i < 1024; i += 256) {
            int tok = i >> 3, u8 = i & 7;
            *(half8v*)&u.st.A[tok * 72 + u8 * 8] =
                *(const half8v*)&hbuf16[(size_t)(t0 + tok) * C4 + kp * 64 + u8 * 8];
        }
        for (int i = tid; i < 1024; i += 256) {
            int jj = i >> 4, seg = i & 15;
            float4 v4 = *(const float4*)&fw[(size_t)jj * C4 + kp * 64 + seg * 4];
            half4v h4 = { (_Float16)v4.x, (_Float16)v4.y, (_Float16)v4.z, (_Float16)v4.w };
            *(half4v*)&u.st.B[jj * 72 + seg * 4] = h4;
        }
        __syncthreads();
#pragma unroll
        for (int ks = 0; ks < 64; ks += 32) {
            half8v a[2], bfr[4];
#pragma unroll
            for (int mf = 0; mf < 2; ++mf)
                a[mf] = *(const half8v*)&u.st.A[(mt0 + mf * 16 + l16) * 72 + ks + quad * 8];
#pragma unroll
            for (int nf = 0; nf < 4; ++nf)
                bfr[nf] = *(const half8v*)&u.st.B[(nf * 16 + l16) * 72 + ks + quad * 8];
#pragma unroll
            for (int mf = 0; mf < 2; ++mf)
#pragma unroll
                for (int nf = 0; nf < 4; ++nf) acc[mf][nf] = MFMA16(a[mf], bfr[nf], acc[mf][nf]);
        }
    }
    __syncthreads();
#pragma unroll
    for (int mf = 0; mf < 2; ++mf)
#pragma unroll
        for (int nf = 0; nf < 4; ++nf) {
            int j = nf * 16 + l16;
            float bias = fb_s[j];
#pragma unroll
            for (int r = 0; r < 4; ++r) {
                int tl = mt0 + mf * 16 + quad * 4 + r;
                float v = acc[mf][nf][r] + bias + (float)x2_16[(size_t)(t0 + tl) * 64 + j];
                u.tr[j * 132 + tl] = v;
            }
        }
    __syncthreads();
    int n = t0 >> 14, hw0 = t0 & (HWSZ - 1);
    for (int i = tid; i < 64 * 32; i += 256) {
        int j = i >> 5, seg = i & 31;
        float4 v = *(const float4*)&u.tr[j * 132 + seg * 4];
        *(float4*)&out[((size_t)(n * CC + j) << 14) + hw0 + seg * 4] = v;
    }
}

extern "C" void kernel_launch(void* const* d_in, const int* in_sizes, int n_in,
                              void* d_out, int out_size, void* d_ws, size_t ws_size,
                              hipStream_t stream) {
    const float* x      = (const float*)d_in[0];
    const float* qkv_w  = (const float*)d_in[1];
    const float* qkv_b  = (const float*)d_in[2];
    const float* proj_w = (const float*)d_in[3];
    const float* proj_b = (const float*)d_in[4];
    const float* rpb    = (const float*)d_in[5];
    const float* ln1_w  = (const float*)d_in[6];
    const float* ln1_b  = (const float*)d_in[7];
    const float* ln2_w  = (const float*)d_in[8];
    const float* ln2_b  = (const float*)d_in[9];
    const float* fc1_w  = (const float*)d_in[10];
    const float* fc1_b  = (const float*)d_in[11];
    const float* fc2_w  = (const float*)d_in[12];
    const float* fc2_b  = (const float*)d_in[13];
    float* out = (float*)d_out;
    char* ws = (char*)d_ws;

    _Float16* qkv16  = (_Float16*)(ws);                 // 12.58 MB [T][192]
    _Float16* attn16 = (_Float16*)(ws + 12582912);      //  4.19 MB [T][64]
    _Float16* x2_16  = (_Float16*)(ws + 16777216);      //  4.19 MB [T][64]
    _Float16* hbuf16 = (_Float16*)(ws + 20971520);      // 16.78 MB [T][256]

    k_qkvln  <<<256,  256, 0, stream>>>(x, ln1_w, ln1_b, qkv_w, qkv_b, qkv16);
    k_attn   <<<1024, 256, 0, stream>>>(qkv16, rpb, attn16);
    k_projfc1<<<256,  256, 0, stream>>>(attn16, proj_w, proj_b, x, ln2_w, ln2_b,
                                        fc1_w, fc1_b, x2_16, hbuf16);
    k_fc2    <<<256,  256, 0, stream>>>(hbuf16, fc2_w, fc2_b, x2_16, out);
}

// Round 9
// 149.579 us; speedup vs baseline: 1.1214x; 1.1214x over previous
//
#include <hip/hip_runtime.h>
#include <math.h>

#define TQ   32768
#define HWSZ 16384
#define CC   64
#define HH   128
#define WW   128
#define C3   192
#define C4   256
#define KS   7

typedef _Float16 half2v __attribute__((ext_vector_type(2)));
typedef _Float16 half4v __attribute__((ext_vector_type(4)));
typedef _Float16 half8v __attribute__((ext_vector_type(8)));
typedef float    f32x4  __attribute__((ext_vector_type(4)));

#define MFMA16(a, b, c) __builtin_amdgcn_mfma_f32_16x16x32_f16((a), (b), (c), 0, 0, 0)

// ============ K1: LN1 + QKV GEMM, all 192 cols per block. grid 256 (R8 version) ============
__global__ __launch_bounds__(256) void k_qkvln(const float* __restrict__ x,
        const float* __restrict__ lnw, const float* __restrict__ lnb,
        const float* __restrict__ qw, const float* __restrict__ qb,
        _Float16* __restrict__ qkv16) {
    __shared__ union {
        struct { __align__(16) _Float16 A[128 * 72]; __align__(16) _Float16 B[192 * 72]; } st;
        __align__(16) _Float16 outb[128 * 200];
    } u;
    __shared__ float ps1[256], ps2[256], m_s[128], r_s[128];
    __shared__ float w_s[64], b_s[64], bias_s[192];
    int tid = threadIdx.x;
    int t0 = blockIdx.x * 128;
    if (tid < 64) { w_s[tid] = lnw[tid]; b_s[tid] = lnb[tid]; }
    if (tid < 192) bias_s[tid] = qb[tid];
    int tok = tid & 127, cq = tid >> 7;
    int t = t0 + tok;
    int n = t >> 14, hw = t & (HWSZ - 1);
    const float* xr = x + ((size_t)n << 20) + hw;
    float v[32];
    float s = 0.f, s2 = 0.f;
#pragma unroll
    for (int e = 0; e < 32; ++e) {
        float f = xr[(cq * 32 + e) * HWSZ];
        v[e] = f; s += f; s2 += f * f;
    }
    ps1[tid] = s; ps2[tid] = s2;
    for (int i = tid; i < 3072; i += 256) {
        int jj = i >> 4, seg = i & 15;
        float4 v4 = *(const float4*)&qw[(size_t)jj * 64 + seg * 4];
        half4v h4 = { (_Float16)v4.x, (_Float16)v4.y, (_Float16)v4.z, (_Float16)v4.w };
        *(half4v*)&u.st.B[jj * 72 + seg * 4] = h4;
    }
    __syncthreads();
    if (tid < 128) {
        float ss = ps1[tid] + ps1[tid + 128];
        float qq = ps2[tid] + ps2[tid + 128];
        float m = ss * (1.f / 64.f);
        float var = qq * (1.f / 64.f) - m * m;
        m_s[tid] = m; r_s[tid] = rsqrtf(var + 1e-5f);
    }
    __syncthreads();
    {
        float m = m_s[tok], r = r_s[tok];
#pragma unroll
        for (int u8 = 0; u8 < 4; ++u8) {
            half8v o;
#pragma unroll
            for (int e = 0; e < 8; ++e) {
                int c = cq * 32 + u8 * 8 + e;
                o[e] = (_Float16)((v[u8 * 8 + e] - m) * r * w_s[c] + b_s[c]);
            }
            *(half8v*)&u.st.A[tok * 72 + cq * 32 + u8 * 8] = o;
        }
    }
    __syncthreads();
    int lane = tid & 63, wv = tid >> 6;
    int quad = lane >> 4, l16 = lane & 15;
    int mt0 = (wv & 1) * 64, nt0 = (wv >> 1) * 96;
    f32x4 acc[4][6];
#pragma unroll
    for (int mf = 0; mf < 4; ++mf)
#pragma unroll
        for (int nf = 0; nf < 6; ++nf) acc[mf][nf] = (f32x4){0.f, 0.f, 0.f, 0.f};
#pragma unroll
    for (int ks = 0; ks < 64; ks += 32) {
        half8v a[4], bfr[6];
#pragma unroll
        for (int mf = 0; mf < 4; ++mf)
            a[mf] = *(const half8v*)&u.st.A[(mt0 + mf * 16 + l16) * 72 + ks + quad * 8];
#pragma unroll
        for (int nf = 0; nf < 6; ++nf)
            bfr[nf] = *(const half8v*)&u.st.B[(nt0 + nf * 16 + l16) * 72 + ks + quad * 8];
#pragma unroll
        for (int mf = 0; mf < 4; ++mf)
#pragma unroll
            for (int nf = 0; nf < 6; ++nf) acc[mf][nf] = MFMA16(a[mf], bfr[nf], acc[mf][nf]);
    }
    __syncthreads();
    const float qscale = 0.17677669529663687f;
#pragma unroll
    for (int mf = 0; mf < 4; ++mf)
#pragma unroll
        for (int nf = 0; nf < 6; ++nf) {
            int j = nt0 + nf * 16 + l16;
            float bias = bias_s[j];
            float sc = (j < 64) ? qscale : 1.f;
#pragma unroll
            for (int r = 0; r < 4; ++r) {
                int tl = mt0 + mf * 16 + quad * 4 + r;
                u.outb[tl * 200 + j] = (_Float16)((acc[mf][nf][r] + bias) * sc);
            }
        }
    __syncthreads();
    for (int i = tid; i < 4096; i += 256) {
        int tk = i >> 5, rem = i & 31;
        if (rem < 24)
            *(half8v*)&qkv16[(size_t)(t0 + tk) * C3 + rem * 8] =
                *(const half8v*)&u.outb[tk * 200 + rem * 8];
    }
}

// ============ K2: tiled neighborhood attention, two heads per block (R4 version) ============
#define KV_STRIDE 136
#define QS_STRIDE 80
#define SS_STRIDE 50

__global__ __launch_bounds__(256) void k_attn(const _Float16* __restrict__ qkv16,
        const float* __restrict__ rpb, _Float16* __restrict__ out) {
    __shared__ __align__(16) _Float16 kv_s[196 * KV_STRIDE];
    __shared__ __align__(16) _Float16 q_s[64 * QS_STRIDE];
    __shared__ __align__(16) _Float16 s_s[128 * SS_STRIDE];
    __shared__ float rpb_s[338];

    int tid = threadIdx.x;
    int bx = blockIdx.x;
    int n  = bx >> 8;
    int th = (bx >> 4) & 15, tw = bx & 15;
    int h0 = th * 8, w0 = tw * 8;
    int wr0 = min(max(h0 - 3, 0), HH - 14);
    int ww0 = min(max(w0 - 3, 0), WW - 14);
    int tbase = n << 14;

    for (int i = tid; i < 338; i += 256) rpb_s[i] = rpb[i];
    for (int i = tid; i < 196 * 16; i += 256) {
        int tok = i >> 4, u = i & 15;
        int wi = tok / 14, wj = tok - wi * 14;
        *(half8v*)&kv_s[tok * KV_STRIDE + u * 8] = *(const half8v*)&qkv16[
            (size_t)(tbase + (wr0 + wi) * WW + ww0 + wj) * C3 + 64 + u * 8];
    }
    for (int i = tid; i < 64 * 8; i += 256) {
        int q = i >> 3, u = i & 7;
        int qg = tbase + (h0 + (q >> 3)) * WW + (w0 + (q & 7));
        *(half8v*)&q_s[q * QS_STRIDE + u * 8] = *(const half8v*)&qkv16[(size_t)qg * C3 + u * 8];
    }
    __syncthreads();

    int half_ = tid & 1, z = (tid >> 1) & 1, q = tid >> 2;
    int qy = q >> 3, qx = q & 7;
    int h = h0 + qy, wc = w0 + qx;
    int sh = min(max(h - 3, 0), HH - KS);
    int sw = min(max(wc - 3, 0), WW - KS);
    int oh = sh - wr0, ow = sw - ww0;
    int dhp = h - sh + 6, dwp = wc - sw + 6;
    {
        const half8v* qp = (const half8v*)&q_s[q * QS_STRIDE + z * 32];
        half8v q0 = qp[0], q1 = qp[1], q2 = qp[2], q3 = qp[3];
        int i7 = 0, j7 = half_;
        for (int nb = half_; nb < 49; nb += 2) {
            int tok = (oh + i7) * 14 + (ow + j7);
            const half8v* kp = (const half8v*)&kv_s[tok * KV_STRIDE + z * 32];
            half2v acc2 = { (_Float16)0.f, (_Float16)0.f };
            half8v k0 = kp[0], k1 = kp[1], k2 = kp[2], k3 = kp[3];
            acc2 += (half2v){k0.s0, k0.s1} * (half2v){q0.s0, q0.s1};
            acc2 += (half2v){k0.s2, k0.s3} * (half2v){q0.s2, q0.s3};
            acc2 += (half2v){k0.s4, k0.s5} * (half2v){q0.s4, q0.s5};
            acc2 += (half2v){k0.s6, k0.s7} * (half2v){q0.s6, q0.s7};
            acc2 += (half2v){k1.s0, k1.s1} * (half2v){q1.s0, q1.s1};
            acc2 += (half2v){k1.s2, k1.s3} * (half2v){q1.s2, q1.s3};
            acc2 += (half2v){k1.s4, k1.s5} * (half2v){q1.s4, q1.s5};
            acc2 += (half2v){k1.s6, k1.s7} * (half2v){q1.s6, q1.s7};
            acc2 += (half2v){k2.s0, k2.s1} * (half2v){q2.s0, q2.s1};
            acc2 += (half2v){k2.s2, k2.s3} * (half2v){q2.s2, q2.s3};
            acc2 += (half2v){k2.s4, k2.s5} * (half2v){q2.s4, q2.s5};
            acc2 += (half2v){k2.s6, k2.s7} * (half2v){q2.s6, q2.s7};
            acc2 += (half2v){k3.s0, k3.s1} * (half2v){q3.s0, q3.s1};
            acc2 += (half2v){k3.s2, k3.s3} * (half2v){q3.s2, q3.s3};
            acc2 += (half2v){k3.s4, k3.s5} * (half2v){q3.s4, q3.s5};
            acc2 += (half2v){k3.s6, k3.s7} * (half2v){q3.s6, q3.s7};
            float s = (float)acc2.x + (float)acc2.y
                    + rpb_s[(z * 13 + (dhp - i7)) * 13 + (dwp - j7)];
            s_s[(q * 2 + z) * SS_STRIDE + nb] = (_Float16)s;
            j7 += 2;
            if (j7 >= 7) { j7 -= 7; ++i7; }
        }
    }
    __syncthreads();

    if (tid < 128) {
        _Float16* sp = &s_s[tid * SS_STRIDE];
        float mx = -1e30f;
        for (int i = 0; i < 49; ++i) mx = fmaxf(mx, (float)sp[i]);
        float sum = 0.f;
        for (int i = 0; i < 49; ++i) {
            float e = __expf((float)sp[i] - mx);
            sum += e;
            sp[i] = (_Float16)e;
        }
        float inv = 1.f / sum;
        for (int i = 0; i < 49; ++i) sp[i] = (_Float16)((float)sp[i] * inv);
    }
    __syncthreads();

    {
        int c16 = half_;
        const _Float16* pp = &s_s[(q * 2 + z) * SS_STRIDE];
        half2v acc[8];
#pragma unroll
        for (int j = 0; j < 8; ++j) acc[j] = (half2v){ (_Float16)0.f, (_Float16)0.f };
        int i7 = 0, j7 = 0;
        for (int nb = 0; nb < 49; ++nb) {
            int tok = (oh + i7) * 14 + (ow + j7);
            _Float16 p = pp[nb];
            half2v p2 = { p, p };
            const half8v* vp = (const half8v*)&kv_s[tok * KV_STRIDE + 64 + z * 32 + c16 * 16];
            half8v v0 = vp[0], v1 = vp[1];
            acc[0] += (half2v){v0.s0, v0.s1} * p2;
            acc[1] += (half2v){v0.s2, v0.s3} * p2;
            acc[2] += (half2v){v0.s4, v0.s5} * p2;
            acc[3] += (half2v){v0.s6, v0.s7} * p2;
            acc[4] += (half2v){v1.s0, v1.s1} * p2;
            acc[5] += (half2v){v1.s2, v1.s3} * p2;
            acc[6] += (half2v){v1.s4, v1.s5} * p2;
            acc[7] += (half2v){v1.s6, v1.s7} * p2;
            ++j7;
            if (j7 == 7) { j7 = 0; ++i7; }
        }
        int qg = tbase + h * WW + wc;
        _Float16* op = out + (size_t)qg * CC + z * 32 + c16 * 16;
        half8v o0 = {acc[0].x, acc[0].y, acc[1].x, acc[1].y, acc[2].x, acc[2].y, acc[3].x, acc[3].y};
        half8v o1 = {acc[4].x, acc[4].y, acc[5].x, acc[5].y, acc[6].x, acc[6].y, acc[7].x, acc[7].y};
        *(half8v*)op = o0;
        *(half8v*)(op + 8) = o1;
    }
}

// ============ K3: proj GEMM + residual(x NCHW) + LN2 fused. grid 256 (R7 version) ============
__global__ __launch_bounds__(256) void k_projln(const _Float16* __restrict__ ain,
        const float* __restrict__ pw, const float* __restrict__ pb,
        const float* __restrict__ x,
        const float* __restrict__ ln2w, const float* __restrict__ ln2b,
        _Float16* __restrict__ x2_16, _Float16* __restrict__ xn2_16) {
    __shared__ union {
        struct { __align__(16) _Float16 A[128 * 72]; __align__(16) _Float16 B[64 * 72]; } st;
        float x2t[128 * 67];
    } u;
    __shared__ float ps1[256], ps2[256], m_s[128], r_s[128];
    __shared__ float w_s[64], b_s[64], pbias[64];
    int tid = threadIdx.x;
    int t0 = blockIdx.x * 128;
    int n = t0 >> 14, hw0 = t0 & (HWSZ - 1);
    if (tid < 64) { w_s[tid] = ln2w[tid]; b_s[tid] = ln2b[tid]; pbias[tid] = pb[tid]; }
    for (int i = tid; i < 1024; i += 256) {
        int tok = i >> 3, u8 = i & 7;
        *(half8v*)&u.st.A[tok * 72 + u8 * 8] = *(const half8v*)&ain[(size_t)(t0 + tok) * 64 + u8 * 8];
    }
    for (int i = tid; i < 1024; i += 256) {
        int jj = i >> 4, seg = i & 15;
        float4 v4 = *(const float4*)&pw[(size_t)jj * 64 + seg * 4];
        half4v h4 = { (_Float16)v4.x, (_Float16)v4.y, (_Float16)v4.z, (_Float16)v4.w };
        *(half4v*)&u.st.B[jj * 72 + seg * 4] = h4;
    }
    __syncthreads();
    int lane = tid & 63, wv = tid >> 6;
    int quad = lane >> 4, l16 = lane & 15;
    int mt0 = wv * 32;
    f32x4 acc[2][4];
#pragma unroll
    for (int mf = 0; mf < 2; ++mf)
#pragma unroll
        for (int nf = 0; nf < 4; ++nf) acc[mf][nf] = (f32x4){0.f, 0.f, 0.f, 0.f};
#pragma unroll
    for (int ks = 0; ks < 64; ks += 32) {
        half8v a[2], bfr[4];
#pragma unroll
        for (int mf = 0; mf < 2; ++mf)
            a[mf] = *(const half8v*)&u.st.A[(mt0 + mf * 16 + l16) * 72 + ks + quad * 8];
#pragma unroll
        for (int nf = 0; nf < 4; ++nf)
            bfr[nf] = *(const half8v*)&u.st.B[(nf * 16 + l16) * 72 + ks + quad * 8];
#pragma unroll
        for (int mf = 0; mf < 2; ++mf)
#pragma unroll
            for (int nf = 0; nf < 4; ++nf) acc[mf][nf] = MFMA16(a[mf], bfr[nf], acc[mf][nf]);
    }
    __syncthreads();
#pragma unroll
    for (int mf = 0; mf < 2; ++mf)
#pragma unroll
        for (int nf = 0; nf < 4; ++nf) {
            int j = nf * 16 + l16;
            float bias = pbias[j];
            int hwl = hw0 + mt0 + mf * 16 + quad * 4;
            float4 rx = *(const float4*)&x[((size_t)(n * CC + j) << 14) + hwl];
#pragma unroll
            for (int r = 0; r < 4; ++r) {
                int tl = mt0 + mf * 16 + quad * 4 + r;
                u.x2t[tl * 67 + j] = acc[mf][nf][r] + bias + ((const float*)&rx)[r];
            }
        }
    __syncthreads();
    int tok = tid & 127, cq = tid >> 7;
    {
        float s = 0.f, s2 = 0.f;
#pragma unroll
        for (int e = 0; e < 32; ++e) {
            float f = u.x2t[tok * 67 + cq * 32 + e];
            s += f; s2 += f * f;
        }
        ps1[tid] = s; ps2[tid] = s2;
    }
    __syncthreads();
    if (tid < 128) {
        float ss = ps1[tid] + ps1[tid + 128];
        float qq = ps2[tid] + ps2[tid + 128];
        float m = ss * (1.f / 64.f);
        float var = qq * (1.f / 64.f) - m * m;
        m_s[tid] = m; r_s[tid] = rsqrtf(var + 1e-5f);
    }
    __syncthreads();
    {
        float m = m_s[tok], r = r_s[tok];
#pragma unroll
        for (int u8 = 0; u8 < 4; ++u8) {
            half8v hv, nv;
#pragma unroll
            for (int e = 0; e < 8; ++e) {
                int c = cq * 32 + u8 * 8 + e;
                float f = u.x2t[tok * 67 + c];
                hv[e] = (_Float16)f;
                nv[e] = (_Float16)((f - m) * r * w_s[c] + b_s[c]);
            }
            size_t base = (size_t)(t0 + tok) * 64 + cq * 32 + u8 * 8;
            *(half8v*)&x2_16[base] = hv;
            *(half8v*)&xn2_16[base] = nv;
        }
    }
}

// ============ K4: FC1 GEMM + exact GELU (R4 version, grid 512) ============
__global__ __launch_bounds__(256) void k_fc1(const _Float16* __restrict__ xin,
        const float* __restrict__ fw, const float* __restrict__ fb,
        _Float16* __restrict__ hbuf16) {
    __shared__ __align__(16) _Float16 A_s[128 * 72];
    __shared__ __align__(16) _Float16 B_s[128 * 72];
    __shared__ float bias_s[128];
    int tid = threadIdx.x;
    int t0 = (blockIdx.x >> 1) * 128;
    int j0 = (blockIdx.x & 1) * 128;
    for (int i = tid; i < 1024; i += 256) {
        int tok = i >> 3, u8 = i & 7;
        *(half8v*)&A_s[tok * 72 + u8 * 8] = *(const half8v*)&xin[(size_t)(t0 + tok) * 64 + u8 * 8];
    }
    for (int i = tid; i < 2048; i += 256) {
        int jj = i >> 4, seg = i & 15;
        float4 v4 = *(const float4*)&fw[(size_t)(j0 + jj) * 64 + seg * 4];
        half4v h4 = { (_Float16)v4.x, (_Float16)v4.y, (_Float16)v4.z, (_Float16)v4.w };
        *(half4v*)&B_s[jj * 72 + seg * 4] = h4;
    }
    if (tid < 128) bias_s[tid] = fb[j0 + tid];
    __syncthreads();
    int lane = tid & 63, wv = tid >> 6;
    int quad = lane >> 4, l16 = lane & 15;
    int mt0 = (wv & 1) * 64, nt0 = (wv >> 1) * 64;
    f32x4 acc[4][4];
#pragma unroll
    for (int mf = 0; mf < 4; ++mf)
#pragma unroll
        for (int nf = 0; nf < 4; ++nf) acc[mf][nf] = (f32x4){0.f, 0.f, 0.f, 0.f};
#pragma unroll
    for (int ks = 0; ks < 64; ks += 32) {
        half8v a[4], bfr[4];
#pragma unroll
        for (int mf = 0; mf < 4; ++mf)
            a[mf] = *(const half8v*)&A_s[(mt0 + mf * 16 + l16) * 72 + ks + quad * 8];
#pragma unroll
        for (int nf = 0; nf < 4; ++nf)
            bfr[nf] = *(const half8v*)&B_s[(nt0 + nf * 16 + l16) * 72 + ks + quad * 8];
#pragma unroll
        for (int mf = 0; mf < 4; ++mf)
#pragma unroll
            for (int nf = 0; nf < 4; ++nf) acc[mf][nf] = MFMA16(a[mf], bfr[nf], acc[mf][nf]);
    }
#pragma unroll
    for (int mf = 0; mf < 4; ++mf)
#pragma unroll
        for (int nf = 0; nf < 4; ++nf) {
            int j = j0 + nt0 + nf * 16 + l16;
            float bias = bias_s[nt0 + nf * 16 + l16];
#pragma unroll
            for (int r = 0; r < 4; ++r) {
                int t = t0 + mt0 + mf * 16 + quad * 4 + r;
                float v = acc[mf][nf][r] + bias;
                float g = 0.5f * v * (1.f + erff(v * 0.70710678118654752f));
                hbuf16[(size_t)t * C4 + j] = (_Float16)g;
            }
        }
}

// ============ K5: FC2 GEMM (K=256) + residual + NCHW f32 out (R4 version, grid 256) ============
__global__ __launch_bounds__(256) void k_fc2(const _Float16* __restrict__ hbuf16,
        const float* __restrict__ fw, const float* __restrict__ fb,
        const _Float16* __restrict__ x2_16, float* __restrict__ out) {
    __shared__ union {
        struct { __align__(16) _Float16 A[128 * 72]; __align__(16) _Float16 B[64 * 72]; } st;
        float tr[64 * 132];
    } u;
    __shared__ float fb_s[64];
    int tid = threadIdx.x;
    int t0 = blockIdx.x * 128;
    int lane = tid & 63, wv = tid >> 6;
    int quad = lane >> 4, l16 = lane & 15;
    int mt0 = wv * 32;
    if (tid < 64) fb_s[tid] = fb[tid];
    f32x4 acc[2][4];
#pragma unroll
    for (int mf = 0; mf < 2; ++mf)
#pragma unroll
        for (int nf = 0; nf < 4; ++nf) acc[mf][nf] = (f32x4){0.f, 0.f, 0.f, 0.f};
    for (int kp = 0; kp < 4; ++kp) {
        if (kp) __syncthreads();
        for (int i = tid; i < 1024; i += 256) {
            int tok = i >> 3, u8 = i & 7;
            *(half8v*)&u.st.A[tok * 72 + u8 * 8] =
                *(const half8v*)&hbuf16[(size_t)(t0 + tok) * C4 + kp * 64 + u8 * 8];
        }
        for (int i = tid; i < 1024; i += 256) {
            int jj = i >> 4, seg = i & 15;
            float4 v4 = *(const float4*)&fw[(size_t)jj * C4 + kp * 64 + seg * 4];
            half4v h4 = { (_Float16)v4.x, (_Float16)v4.y, (_Float16)v4.z, (_Float16)v4.w };
            *(half4v*)&u.st.B[jj * 72 + seg * 4] = h4;
        }
        __syncthreads();
#pragma unroll
        for (int ks = 0; ks < 64; ks += 32) {
            half8v a[2], bfr[4];
#pragma unroll
            for (int mf = 0; mf < 2; ++mf)
                a[mf] = *(const half8v*)&u.st.A[(mt0 + mf * 16 + l16) * 72 + ks + quad * 8];
#pragma unroll
            for (int nf = 0; nf < 4; ++nf)
                bfr[nf] = *(const half8v*)&u.st.B[(nf * 16 + l16) * 72 + ks + quad * 8];
#pragma unroll
            for (int mf = 0; mf < 2; ++mf)
#pragma unroll
                for (int nf = 0; nf < 4; ++nf) acc[mf][nf] = MFMA16(a[mf], bfr[nf], acc[mf][nf]);
        }
    }
    __syncthreads();
#pragma unroll
    for (int mf = 0; mf < 2; ++mf)
#pragma unroll
        for (int nf = 0; nf < 4; ++nf) {
            int j = nf * 16 + l16;
            float bias = fb_s[j];
#pragma unroll
            for (int r = 0; r < 4; ++r) {
                int tl = mt0 + mf * 16 + quad * 4 + r;
                float v = acc[mf][nf][r] + bias + (float)x2_16[(size_t)(t0 + tl) * 64 + j];
                u.tr[j * 132 + tl] = v;
            }
        }
    __syncthreads();
    int n = t0 >> 14, hw0 = t0 & (HWSZ - 1);
    for (int i = tid; i < 64 * 32; i += 256) {
        int j = i >> 5, seg = i & 31;
        float4 v = *(const float4*)&u.tr[j * 132 + seg * 4];
        *(float4*)&out[((size_t)(n * CC + j) << 14) + hw0 + seg * 4] = v;
    }
}

extern "C" void kernel_launch(void* const* d_in, const int* in_sizes, int n_in,
                              void* d_out, int out_size, void* d_ws, size_t ws_size,
                              hipStream_t stream) {
    const float* x      = (const float*)d_in[0];
    const float* qkv_w  = (const float*)d_in[1];
    const float* qkv_b  = (const float*)d_in[2];
    const float* proj_w = (const float*)d_in[3];
    const float* proj_b = (const float*)d_in[4];
    const float* rpb    = (const float*)d_in[5];
    const float* ln1_w  = (const float*)d_in[6];
    const float* ln1_b  = (const float*)d_in[7];
    const float* ln2_w  = (const float*)d_in[8];
    const float* ln2_b  = (const float*)d_in[9];
    const float* fc1_w  = (const float*)d_in[10];
    const float* fc1_b  = (const float*)d_in[11];
    const float* fc2_w  = (const float*)d_in[12];
    const float* fc2_b  = (const float*)d_in[13];
    float* out = (float*)d_out;
    char* ws = (char*)d_ws;

    _Float16* qkv16  = (_Float16*)(ws);                 // 12.58 MB [T][192]
    _Float16* attn16 = (_Float16*)(ws + 12582912);      //  4.19 MB [T][64]
    _Float16* x2_16  = (_Float16*)(ws + 16777216);      //  4.19 MB [T][64]
    _Float16* xn2_16 = (_Float16*)(ws + 20971520);      //  4.19 MB [T][64]
    _Float16* hbuf16 = (_Float16*)(ws + 25165824);      // 16.78 MB [T][256]

    k_qkvln <<<256, 256, 0, stream>>>(x, ln1_w, ln1_b, qkv_w, qkv_b, qkv16);
    k_attn  <<<512, 256, 0, stream>>>(qkv16, rpb, attn16);
    k_projln<<<256, 256, 0, stream>>>(attn16, proj_w, proj_b, x, ln2_w, ln2_b, x2_16, xn2_16);
    k_fc1   <<<512, 256, 0, stream>>>(xn2_16, fc1_w, fc1_b, hbuf16);
    k_fc2   <<<256, 256, 0, stream>>>(hbuf16, fc2_w, fc2_b, x2_16, out);
}

// Round 10
// 142.918 us; speedup vs baseline: 1.1737x; 1.0466x over previous
//
#include <hip/hip_runtime.h>
#include <math.h>

#define TQ   32768
#define HWSZ 16384
#define CC   64
#define HH   128
#define WW   128
#define C3   192
#define C4   256
#define KS   7

typedef _Float16 half2v __attribute__((ext_vector_type(2)));
typedef _Float16 half4v __attribute__((ext_vector_type(4)));
typedef _Float16 half8v __attribute__((ext_vector_type(8)));
typedef float    f32x4  __attribute__((ext_vector_type(4)));

#define MFMA16(a, b, c) __builtin_amdgcn_mfma_f32_16x16x32_f16((a), (b), (c), 0, 0, 0)

// ============ K1: LN1 + QKV GEMM, all 192 cols per block. grid 256 (R8/R9 version) ============
__global__ __launch_bounds__(256) void k_qkvln(const float* __restrict__ x,
        const float* __restrict__ lnw, const float* __restrict__ lnb,
        const float* __restrict__ qw, const float* __restrict__ qb,
        _Float16* __restrict__ qkv16) {
    __shared__ union {
        struct { __align__(16) _Float16 A[128 * 72]; __align__(16) _Float16 B[192 * 72]; } st;
        __align__(16) _Float16 outb[128 * 200];
    } u;
    __shared__ float ps1[256], ps2[256], m_s[128], r_s[128];
    __shared__ float w_s[64], b_s[64], bias_s[192];
    int tid = threadIdx.x;
    int t0 = blockIdx.x * 128;
    if (tid < 64) { w_s[tid] = lnw[tid]; b_s[tid] = lnb[tid]; }
    if (tid < 192) bias_s[tid] = qb[tid];
    int tok = tid & 127, cq = tid >> 7;
    int t = t0 + tok;
    int n = t >> 14, hw = t & (HWSZ - 1);
    const float* xr = x + ((size_t)n << 20) + hw;
    float v[32];
    float s = 0.f, s2 = 0.f;
#pragma unroll
    for (int e = 0; e < 32; ++e) {
        float f = xr[(cq * 32 + e) * HWSZ];
        v[e] = f; s += f; s2 += f * f;
    }
    ps1[tid] = s; ps2[tid] = s2;
    for (int i = tid; i < 3072; i += 256) {
        int jj = i >> 4, seg = i & 15;
        float4 v4 = *(const float4*)&qw[(size_t)jj * 64 + seg * 4];
        half4v h4 = { (_Float16)v4.x, (_Float16)v4.y, (_Float16)v4.z, (_Float16)v4.w };
        *(half4v*)&u.st.B[jj * 72 + seg * 4] = h4;
    }
    __syncthreads();
    if (tid < 128) {
        float ss = ps1[tid] + ps1[tid + 128];
        float qq = ps2[tid] + ps2[tid + 128];
        float m = ss * (1.f / 64.f);
        float var = qq * (1.f / 64.f) - m * m;
        m_s[tid] = m; r_s[tid] = rsqrtf(var + 1e-5f);
    }
    __syncthreads();
    {
        float m = m_s[tok], r = r_s[tok];
#pragma unroll
        for (int u8 = 0; u8 < 4; ++u8) {
            half8v o;
#pragma unroll
            for (int e = 0; e < 8; ++e) {
                int c = cq * 32 + u8 * 8 + e;
                o[e] = (_Float16)((v[u8 * 8 + e] - m) * r * w_s[c] + b_s[c]);
            }
            *(half8v*)&u.st.A[tok * 72 + cq * 32 + u8 * 8] = o;
        }
    }
    __syncthreads();
    int lane = tid & 63, wv = tid >> 6;
    int quad = lane >> 4, l16 = lane & 15;
    int mt0 = (wv & 1) * 64, nt0 = (wv >> 1) * 96;
    f32x4 acc[4][6];
#pragma unroll
    for (int mf = 0; mf < 4; ++mf)
#pragma unroll
        for (int nf = 0; nf < 6; ++nf) acc[mf][nf] = (f32x4){0.f, 0.f, 0.f, 0.f};
#pragma unroll
    for (int ks = 0; ks < 64; ks += 32) {
        half8v a[4], bfr[6];
#pragma unroll
        for (int mf = 0; mf < 4; ++mf)
            a[mf] = *(const half8v*)&u.st.A[(mt0 + mf * 16 + l16) * 72 + ks + quad * 8];
#pragma unroll
        for (int nf = 0; nf < 6; ++nf)
            bfr[nf] = *(const half8v*)&u.st.B[(nt0 + nf * 16 + l16) * 72 + ks + quad * 8];
#pragma unroll
        for (int mf = 0; mf < 4; ++mf)
#pragma unroll
            for (int nf = 0; nf < 6; ++nf) acc[mf][nf] = MFMA16(a[mf], bfr[nf], acc[mf][nf]);
    }
    __syncthreads();
    const float qscale = 0.17677669529663687f;
#pragma unroll
    for (int mf = 0; mf < 4; ++mf)
#pragma unroll
        for (int nf = 0; nf < 6; ++nf) {
            int j = nt0 + nf * 16 + l16;
            float bias = bias_s[j];
            float sc = (j < 64) ? qscale : 1.f;
#pragma unroll
            for (int r = 0; r < 4; ++r) {
                int tl = mt0 + mf * 16 + quad * 4 + r;
                u.outb[tl * 200 + j] = (_Float16)((acc[mf][nf][r] + bias) * sc);
            }
        }
    __syncthreads();
    for (int i = tid; i < 4096; i += 256) {
        int tk = i >> 5, rem = i & 31;
        if (rem < 24)
            *(half8v*)&qkv16[(size_t)(t0 + tk) * C3 + rem * 8] =
                *(const half8v*)&u.outb[tk * 200 + rem * 8];
    }
}

// ============ K2: tiled neighborhood attention, two heads per block (R4/R9 version) ============
#define KV_STRIDE 136
#define QS_STRIDE 80
#define SS_STRIDE 50

__global__ __launch_bounds__(256) void k_attn(const _Float16* __restrict__ qkv16,
        const float* __restrict__ rpb, _Float16* __restrict__ out) {
    __shared__ __align__(16) _Float16 kv_s[196 * KV_STRIDE];
    __shared__ __align__(16) _Float16 q_s[64 * QS_STRIDE];
    __shared__ __align__(16) _Float16 s_s[128 * SS_STRIDE];
    __shared__ float rpb_s[338];

    int tid = threadIdx.x;
    int bx = blockIdx.x;
    int n  = bx >> 8;
    int th = (bx >> 4) & 15, tw = bx & 15;
    int h0 = th * 8, w0 = tw * 8;
    int wr0 = min(max(h0 - 3, 0), HH - 14);
    int ww0 = min(max(w0 - 3, 0), WW - 14);
    int tbase = n << 14;

    for (int i = tid; i < 338; i += 256) rpb_s[i] = rpb[i];
    for (int i = tid; i < 196 * 16; i += 256) {
        int tok = i >> 4, u = i & 15;
        int wi = tok / 14, wj = tok - wi * 14;
        *(half8v*)&kv_s[tok * KV_STRIDE + u * 8] = *(const half8v*)&qkv16[
            (size_t)(tbase + (wr0 + wi) * WW + ww0 + wj) * C3 + 64 + u * 8];
    }
    for (int i = tid; i < 64 * 8; i += 256) {
        int q = i >> 3, u = i & 7;
        int qg = tbase + (h0 + (q >> 3)) * WW + (w0 + (q & 7));
        *(half8v*)&q_s[q * QS_STRIDE + u * 8] = *(const half8v*)&qkv16[(size_t)qg * C3 + u * 8];
    }
    __syncthreads();

    int half_ = tid & 1, z = (tid >> 1) & 1, q = tid >> 2;
    int qy = q >> 3, qx = q & 7;
    int h = h0 + qy, wc = w0 + qx;
    int sh = min(max(h - 3, 0), HH - KS);
    int sw = min(max(wc - 3, 0), WW - KS);
    int oh = sh - wr0, ow = sw - ww0;
    int dhp = h - sh + 6, dwp = wc - sw + 6;
    {
        const half8v* qp = (const half8v*)&q_s[q * QS_STRIDE + z * 32];
        half8v q0 = qp[0], q1 = qp[1], q2 = qp[2], q3 = qp[3];
        int i7 = 0, j7 = half_;
        for (int nb = half_; nb < 49; nb += 2) {
            int tok = (oh + i7) * 14 + (ow + j7);
            const half8v* kp = (const half8v*)&kv_s[tok * KV_STRIDE + z * 32];
            half2v acc2 = { (_Float16)0.f, (_Float16)0.f };
            half8v k0 = kp[0], k1 = kp[1], k2 = kp[2], k3 = kp[3];
            acc2 += (half2v){k0.s0, k0.s1} * (half2v){q0.s0, q0.s1};
            acc2 += (half2v){k0.s2, k0.s3} * (half2v){q0.s2, q0.s3};
            acc2 += (half2v){k0.s4, k0.s5} * (half2v){q0.s4, q0.s5};
            acc2 += (half2v){k0.s6, k0.s7} * (half2v){q0.s6, q0.s7};
            acc2 += (half2v){k1.s0, k1.s1} * (half2v){q1.s0, q1.s1};
            acc2 += (half2v){k1.s2, k1.s3} * (half2v){q1.s2, q1.s3};
            acc2 += (half2v){k1.s4, k1.s5} * (half2v){q1.s4, q1.s5};
            acc2 += (half2v){k1.s6, k1.s7} * (half2v){q1.s6, q1.s7};
            acc2 += (half2v){k2.s0, k2.s1} * (half2v){q2.s0, q2.s1};
            acc2 += (half2v){k2.s2, k2.s3} * (half2v){q2.s2, q2.s3};
            acc2 += (half2v){k2.s4, k2.s5} * (half2v){q2.s4, q2.s5};
            acc2 += (half2v){k2.s6, k2.s7} * (half2v){q2.s6, q2.s7};
            acc2 += (half2v){k3.s0, k3.s1} * (half2v){q3.s0, q3.s1};
            acc2 += (half2v){k3.s2, k3.s3} * (half2v){q3.s2, q3.s3};
            acc2 += (half2v){k3.s4, k3.s5} * (half2v){q3.s4, q3.s5};
            acc2 += (half2v){k3.s6, k3.s7} * (half2v){q3.s6, q3.s7};
            float s = (float)acc2.x + (float)acc2.y
                    + rpb_s[(z * 13 + (dhp - i7)) * 13 + (dwp - j7)];
            s_s[(q * 2 + z) * SS_STRIDE + nb] = (_Float16)s;
            j7 += 2;
            if (j7 >= 7) { j7 -= 7; ++i7; }
        }
    }
    __syncthreads();

    if (tid < 128) {
        _Float16* sp = &s_s[tid * SS_STRIDE];
        float mx = -1e30f;
        for (int i = 0; i < 49; ++i) mx = fmaxf(mx, (float)sp[i]);
        float sum = 0.f;
        for (int i = 0; i < 49; ++i) {
            float e = __expf((float)sp[i] - mx);
            sum += e;
            sp[i] = (_Float16)e;
        }
        float inv = 1.f / sum;
        for (int i = 0; i < 49; ++i) sp[i] = (_Float16)((float)sp[i] * inv);
    }
    __syncthreads();

    {
        int c16 = half_;
        const _Float16* pp = &s_s[(q * 2 + z) * SS_STRIDE];
        half2v acc[8];
#pragma unroll
        for (int j = 0; j < 8; ++j) acc[j] = (half2v){ (_Float16)0.f, (_Float16)0.f };
        int i7 = 0, j7 = 0;
        for (int nb = 0; nb < 49; ++nb) {
            int tok = (oh + i7) * 14 + (ow + j7);
            _Float16 p = pp[nb];
            half2v p2 = { p, p };
            const half8v* vp = (const half8v*)&kv_s[tok * KV_STRIDE + 64 + z * 32 + c16 * 16];
            half8v v0 = vp[0], v1 = vp[1];
            acc[0] += (half2v){v0.s0, v0.s1} * p2;
            acc[1] += (half2v){v0.s2, v0.s3} * p2;
            acc[2] += (half2v){v0.s4, v0.s5} * p2;
            acc[3] += (half2v){v0.s6, v0.s7} * p2;
            acc[4] += (half2v){v1.s0, v1.s1} * p2;
            acc[5] += (half2v){v1.s2, v1.s3} * p2;
            acc[6] += (half2v){v1.s4, v1.s5} * p2;
            acc[7] += (half2v){v1.s6, v1.s7} * p2;
            ++j7;
            if (j7 == 7) { j7 = 0; ++i7; }
        }
        int qg = tbase + h * WW + wc;
        _Float16* op = out + (size_t)qg * CC + z * 32 + c16 * 16;
        half8v o0 = {acc[0].x, acc[0].y, acc[1].x, acc[1].y, acc[2].x, acc[2].y, acc[3].x, acc[3].y};
        half8v o1 = {acc[4].x, acc[4].y, acc[5].x, acc[5].y, acc[6].x, acc[6].y, acc[7].x, acc[7].y};
        *(half8v*)op = o0;
        *(half8v*)(op + 8) = o1;
    }
}

// ============ K3: proj GEMM + residual(x NCHW) + LN2 fused. grid 256 (R7/R9 version) ============
__global__ __launch_bounds__(256) void k_projln(const _Float16* __restrict__ ain,
        const float* __restrict__ pw, const float* __restrict__ pb,
        const float* __restrict__ x,
        const float* __restrict__ ln2w, const float* __restrict__ ln2b,
        _Float16* __restrict__ x2_16, _Float16* __restrict__ xn2_16) {
    __shared__ union {
        struct { __align__(16) _Float16 A[128 * 72]; __align__(16) _Float16 B[64 * 72]; } st;
        float x2t[128 * 67];
    } u;
    __shared__ float ps1[256], ps2[256], m_s[128], r_s[128];
    __shared__ float w_s[64], b_s[64], pbias[64];
    int tid = threadIdx.x;
    int t0 = blockIdx.x * 128;
    int n = t0 >> 14, hw0 = t0 & (HWSZ - 1);
    if (tid < 64) { w_s[tid] = ln2w[tid]; b_s[tid] = ln2b[tid]; pbias[tid] = pb[tid]; }
    for (int i = tid; i < 1024; i += 256) {
        int tok = i >> 3, u8 = i & 7;
        *(half8v*)&u.st.A[tok * 72 + u8 * 8] = *(const half8v*)&ain[(size_t)(t0 + tok) * 64 + u8 * 8];
    }
    for (int i = tid; i < 1024; i += 256) {
        int jj = i >> 4, seg = i & 15;
        float4 v4 = *(const float4*)&pw[(size_t)jj * 64 + seg * 4];
        half4v h4 = { (_Float16)v4.x, (_Float16)v4.y, (_Float16)v4.z, (_Float16)v4.w };
        *(half4v*)&u.st.B[jj * 72 + seg * 4] = h4;
    }
    __syncthreads();
    int lane = tid & 63, wv = tid >> 6;
    int quad = lane >> 4, l16 = lane & 15;
    int mt0 = wv * 32;
    f32x4 acc[2][4];
#pragma unroll
    for (int mf = 0; mf < 2; ++mf)
#pragma unroll
        for (int nf = 0; nf < 4; ++nf) acc[mf][nf] = (f32x4){0.f, 0.f, 0.f, 0.f};
#pragma unroll
    for (int ks = 0; ks < 64; ks += 32) {
        half8v a[2], bfr[4];
#pragma unroll
        for (int mf = 0; mf < 2; ++mf)
            a[mf] = *(const half8v*)&u.st.A[(mt0 + mf * 16 + l16) * 72 + ks + quad * 8];
#pragma unroll
        for (int nf = 0; nf < 4; ++nf)
            bfr[nf] = *(const half8v*)&u.st.B[(nf * 16 + l16) * 72 + ks + quad * 8];
#pragma unroll
        for (int mf = 0; mf < 2; ++mf)
#pragma unroll
            for (int nf = 0; nf < 4; ++nf) acc[mf][nf] = MFMA16(a[mf], bfr[nf], acc[mf][nf]);
    }
    __syncthreads();
#pragma unroll
    for (int mf = 0; mf < 2; ++mf)
#pragma unroll
        for (int nf = 0; nf < 4; ++nf) {
            int j = nf * 16 + l16;
            float bias = pbias[j];
            int hwl = hw0 + mt0 + mf * 16 + quad * 4;
            float4 rx = *(const float4*)&x[((size_t)(n * CC + j) << 14) + hwl];
#pragma unroll
            for (int r = 0; r < 4; ++r) {
                int tl = mt0 + mf * 16 + quad * 4 + r;
                u.x2t[tl * 67 + j] = acc[mf][nf][r] + bias + ((const float*)&rx)[r];
            }
        }
    __syncthreads();
    int tok = tid & 127, cq = tid >> 7;
    {
        float s = 0.f, s2 = 0.f;
#pragma unroll
        for (int e = 0; e < 32; ++e) {
            float f = u.x2t[tok * 67 + cq * 32 + e];
            s += f; s2 += f * f;
        }
        ps1[tid] = s; ps2[tid] = s2;
    }
    __syncthreads();
    if (tid < 128) {
        float ss = ps1[tid] + ps1[tid + 128];
        float qq = ps2[tid] + ps2[tid + 128];
        float m = ss * (1.f / 64.f);
        float var = qq * (1.f / 64.f) - m * m;
        m_s[tid] = m; r_s[tid] = rsqrtf(var + 1e-5f);
    }
    __syncthreads();
    {
        float m = m_s[tok], r = r_s[tok];
#pragma unroll
        for (int u8 = 0; u8 < 4; ++u8) {
            half8v hv, nv;
#pragma unroll
            for (int e = 0; e < 8; ++e) {
                int c = cq * 32 + u8 * 8 + e;
                float f = u.x2t[tok * 67 + c];
                hv[e] = (_Float16)f;
                nv[e] = (_Float16)((f - m) * r * w_s[c] + b_s[c]);
            }
            size_t base = (size_t)(t0 + tok) * 64 + cq * 32 + u8 * 8;
            *(half8v*)&x2_16[base] = hv;
            *(half8v*)&xn2_16[base] = nv;
        }
    }
}

// ============ K4: fused MLP (fc1 + GELU + fc2 + residual + NCHW out). grid 512, 64-token blocks ============
// h tile lives in LDS (64x264 f16) — kills the 33.6 MB hbuf round-trip and one kernel gap.
__global__ __launch_bounds__(256) void k_mlp(const _Float16* __restrict__ xn2,
        const _Float16* __restrict__ x2_16,
        const float* __restrict__ f1w, const float* __restrict__ f1b,
        const float* __restrict__ f2w, const float* __restrict__ f2b,
        float* __restrict__ out) {
    __shared__ __align__(16) _Float16 H_s[64 * 264];    // 33.8 KB
    __shared__ union {
        struct { __align__(16) _Float16 A[64 * 72]; __align__(16) _Float16 B[128 * 72]; } st;
        float tr[64 * 68];                              // 17.4 KB < 27.6 KB
    } u;
    __shared__ float f1b_s[256], f2b_s[64];
    int tid = threadIdx.x;
    int t0 = blockIdx.x * 64;
    int lane = tid & 63, wv = tid >> 6;
    int quad = lane >> 4, l16 = lane & 15;
    f1b_s[tid] = f1b[tid];
    if (tid < 64) f2b_s[tid] = f2b[tid];
    // stage A: xn2 tile (64 tokens x 64 ch)
    for (int i = tid; i < 512; i += 256) {
        int tok = i >> 3, u8 = i & 7;
        *(half8v*)&u.st.A[tok * 72 + u8 * 8] = *(const half8v*)&xn2[(size_t)(t0 + tok) * 64 + u8 * 8];
    }
    // ---- fc1: two 128-j halves, GELU -> H_s ----
    for (int jh = 0; jh < 2; ++jh) {
        if (jh) __syncthreads();   // prior MFMA reads of B done before restage
        for (int i = tid; i < 2048; i += 256) {
            int jj = i >> 4, seg = i & 15;
            float4 v4 = *(const float4*)&f1w[(size_t)(jh * 128 + jj) * 64 + seg * 4];
            half4v h4 = { (_Float16)v4.x, (_Float16)v4.y, (_Float16)v4.z, (_Float16)v4.w };
            *(half4v*)&u.st.B[jj * 72 + seg * 4] = h4;
        }
        __syncthreads();
        int mt0 = (wv & 1) * 32, nt0 = (wv >> 1) * 64;
        f32x4 acc[2][4];
#pragma unroll
        for (int mf = 0; mf < 2; ++mf)
#pragma unroll
            for (int nf = 0; nf < 4; ++nf) acc[mf][nf] = (f32x4){0.f, 0.f, 0.f, 0.f};
#pragma unroll
        for (int ks = 0; ks < 64; ks += 32) {
            half8v a[2], bfr[4];
#pragma unroll
            for (int mf = 0; mf < 2; ++mf)
                a[mf] = *(const half8v*)&u.st.A[(mt0 + mf * 16 + l16) * 72 + ks + quad * 8];
#pragma unroll
            for (int nf = 0; nf < 4; ++nf)
                bfr[nf] = *(const half8v*)&u.st.B[(nt0 + nf * 16 + l16) * 72 + ks + quad * 8];
#pragma unroll
            for (int mf = 0; mf < 2; ++mf)
#pragma unroll
                for (int nf = 0; nf < 4; ++nf) acc[mf][nf] = MFMA16(a[mf], bfr[nf], acc[mf][nf]);
        }
#pragma unroll
        for (int mf = 0; mf < 2; ++mf)
#pragma unroll
            for (int nf = 0; nf < 4; ++nf) {
                int jl = nt0 + nf * 16 + l16;
                float bias = f1b_s[jh * 128 + jl];
#pragma unroll
                for (int r = 0; r < 4; ++r) {
                    int tl = mt0 + mf * 16 + quad * 4 + r;
                    float vv = acc[mf][nf][r] + bias;
                    float g = 0.5f * vv * (1.f + erff(vv * 0.70710678118654752f));
                    H_s[tl * 264 + jh * 128 + jl] = (_Float16)g;
                }
            }
    }
    __syncthreads();   // H complete; B_s free for fc2 panels
    // ---- fc2: 4 K-panels of 64, A = H_s ----
    int mt0 = wv * 16;
    f32x4 acc2[4];
#pragma unroll
    for (int nf = 0; nf < 4; ++nf) acc2[nf] = (f32x4){0.f, 0.f, 0.f, 0.f};
    for (int kp = 0; kp < 4; ++kp) {
        if (kp) __syncthreads();
        for (int i = tid; i < 1024; i += 256) {
            int jj = i >> 4, seg = i & 15;
            float4 v4 = *(const float4*)&f2w[(size_t)jj * C4 + kp * 64 + seg * 4];
            half4v h4 = { (_Float16)v4.x, (_Float16)v4.y, (_Float16)v4.z, (_Float16)v4.w };
            *(half4v*)&u.st.B[jj * 72 + seg * 4] = h4;
        }
        __syncthreads();
#pragma unroll
        for (int ks = 0; ks < 64; ks += 32) {
            half8v a = *(const half8v*)&H_s[(mt0 + l16) * 264 + kp * 64 + ks + quad * 8];
            half8v bfr[4];
#pragma unroll
            for (int nf = 0; nf < 4; ++nf)
                bfr[nf] = *(const half8v*)&u.st.B[(nf * 16 + l16) * 72 + ks + quad * 8];
#pragma unroll
            for (int nf = 0; nf < 4; ++nf) acc2[nf] = MFMA16(a, bfr[nf], acc2[nf]);
        }
    }
    __syncthreads();   // all MFMA reads of B done before tr overwrite
    // ---- epilogue: bias + residual -> transpose tile -> NCHW float4 stores ----
#pragma unroll
    for (int nf = 0; nf < 4; ++nf) {
        int j = nf * 16 + l16;
        float bias = f2b_s[j];
#pragma unroll
        for (int r = 0; r < 4; ++r) {
            int tl = mt0 + quad * 4 + r;
            float v = acc2[nf][r] + bias + (float)x2_16[(size_t)(t0 + tl) * 64 + j];
            u.tr[j * 68 + tl] = v;
        }
    }
    __syncthreads();
    int n = t0 >> 14, hw0 = t0 & (HWSZ - 1);
    for (int i = tid; i < 1024; i += 256) {
        int j = i >> 4, seg = i & 15;
        float4 v = *(const float4*)&u.tr[j * 68 + seg * 4];
        *(float4*)&out[((size_t)(n * CC + j) << 14) + hw0 + seg * 4] = v;
    }
}

extern "C" void kernel_launch(void* const* d_in, const int* in_sizes, int n_in,
                              void* d_out, int out_size, void* d_ws, size_t ws_size,
                              hipStream_t stream) {
    const float* x      = (const float*)d_in[0];
    const float* qkv_w  = (const float*)d_in[1];
    const float* qkv_b  = (const float*)d_in[2];
    const float* proj_w = (const float*)d_in[3];
    const float* proj_b = (const float*)d_in[4];
    const float* rpb    = (const float*)d_in[5];
    const float* ln1_w  = (const float*)d_in[6];
    const float* ln1_b  = (const float*)d_in[7];
    const float* ln2_w  = (const float*)d_in[8];
    const float* ln2_b  = (const float*)d_in[9];
    const float* fc1_w  = (const float*)d_in[10];
    const float* fc1_b  = (const float*)d_in[11];
    const float* fc2_w  = (const float*)d_in[12];
    const float* fc2_b  = (const float*)d_in[13];
    float* out = (float*)d_out;
    char* ws = (char*)d_ws;

    _Float16* qkv16  = (_Float16*)(ws);                 // 12.58 MB [T][192]
    _Float16* attn16 = (_Float16*)(ws + 12582912);      //  4.19 MB [T][64]
    _Float16* x2_16  = (_Float16*)(ws + 16777216);      //  4.19 MB [T][64]
    _Float16* xn2_16 = (_Float16*)(ws + 20971520);      //  4.19 MB [T][64]

    k_qkvln <<<256, 256, 0, stream>>>(x, ln1_w, ln1_b, qkv_w, qkv_b, qkv16);
    k_attn  <<<512, 256, 0, stream>>>(qkv16, rpb, attn16);
    k_projln<<<256, 256, 0, stream>>>(attn16, proj_w, proj_b, x, ln2_w, ln2_b, x2_16, xn2_16);
    k_mlp   <<<512, 256, 0, stream>>>(xn2_16, x2_16, fc1_w, fc1_b, fc2_w, fc2_b, out);
}

// Round 11
// 132.566 us; speedup vs baseline: 1.2653x; 1.0781x over previous
//
#include <hip/hip_runtime.h>
#include <math.h>

#define TQ   32768
#define HWSZ 16384
#define CC   64
#define HH   128
#define WW   128
#define C3   192
#define C4   256
#define KS   7

typedef _Float16 half2v __attribute__((ext_vector_type(2)));
typedef _Float16 half4v __attribute__((ext_vector_type(4)));
typedef _Float16 half8v __attribute__((ext_vector_type(8)));
typedef float    f32x4  __attribute__((ext_vector_type(4)));

#define MFMA16(a, b, c) __builtin_amdgcn_mfma_f32_16x16x32_f16((a), (b), (c), 0, 0, 0)

// ============ K1: LN1 + QKV GEMM + weight-f16 preconvert tail. grid 256 ============
__global__ __launch_bounds__(256) void k_qkvln(const float* __restrict__ x,
        const float* __restrict__ lnw, const float* __restrict__ lnb,
        const float* __restrict__ qw, const float* __restrict__ qb,
        const float* __restrict__ pw, const float* __restrict__ f1w,
        const float* __restrict__ f2w,
        _Float16* __restrict__ qkv16, _Float16* __restrict__ pw16,
        _Float16* __restrict__ f1w16, _Float16* __restrict__ f2w16) {
    __shared__ union {
        struct { __align__(16) _Float16 A[128 * 72]; __align__(16) _Float16 B[192 * 72]; } st;
        __align__(16) _Float16 outb[128 * 200];
    } u;
    __shared__ float ps1[256], ps2[256], m_s[128], r_s[128];
    __shared__ float w_s[64], b_s[64], bias_s[192];
    int tid = threadIdx.x;
    int t0 = blockIdx.x * 128;
    if (tid < 64) { w_s[tid] = lnw[tid]; b_s[tid] = lnb[tid]; }
    if (tid < 192) bias_s[tid] = qb[tid];
    int tok = tid & 127, cq = tid >> 7;
    int t = t0 + tok;
    int n = t >> 14, hw = t & (HWSZ - 1);
    const float* xr = x + ((size_t)n << 20) + hw;
    float v[32];
    float s = 0.f, s2 = 0.f;
#pragma unroll
    for (int e = 0; e < 32; ++e) {
        float f = xr[(cq * 32 + e) * HWSZ];
        v[e] = f; s += f; s2 += f * f;
    }
    ps1[tid] = s; ps2[tid] = s2;
    for (int i = tid; i < 3072; i += 256) {
        int jj = i >> 4, seg = i & 15;
        float4 v4 = *(const float4*)&qw[(size_t)jj * 64 + seg * 4];
        half4v h4 = { (_Float16)v4.x, (_Float16)v4.y, (_Float16)v4.z, (_Float16)v4.w };
        *(half4v*)&u.st.B[jj * 72 + seg * 4] = h4;
    }
    // weight preconvert tail (no LDS involvement): proj 4096, fc1 16384, fc2 16384
    {
        int g = blockIdx.x * 256 + tid;
        if (g < 4096) pw16[g] = (_Float16)pw[g];
        else if (g < 20480) f1w16[g - 4096] = (_Float16)f1w[g - 4096];
        else if (g < 36864) f2w16[g - 20480] = (_Float16)f2w[g - 20480];
    }
    __syncthreads();
    if (tid < 128) {
        float ss = ps1[tid] + ps1[tid + 128];
        float qq = ps2[tid] + ps2[tid + 128];
        float m = ss * (1.f / 64.f);
        float var = qq * (1.f / 64.f) - m * m;
        m_s[tid] = m; r_s[tid] = rsqrtf(var + 1e-5f);
    }
    __syncthreads();
    {
        float m = m_s[tok], r = r_s[tok];
#pragma unroll
        for (int u8 = 0; u8 < 4; ++u8) {
            half8v o;
#pragma unroll
            for (int e = 0; e < 8; ++e) {
                int c = cq * 32 + u8 * 8 + e;
                o[e] = (_Float16)((v[u8 * 8 + e] - m) * r * w_s[c] + b_s[c]);
            }
            *(half8v*)&u.st.A[tok * 72 + cq * 32 + u8 * 8] = o;
        }
    }
    __syncthreads();
    int lane = tid & 63, wv = tid >> 6;
    int quad = lane >> 4, l16 = lane & 15;
    int mt0 = (wv & 1) * 64, nt0 = (wv >> 1) * 96;
    f32x4 acc[4][6];
#pragma unroll
    for (int mf = 0; mf < 4; ++mf)
#pragma unroll
        for (int nf = 0; nf < 6; ++nf) acc[mf][nf] = (f32x4){0.f, 0.f, 0.f, 0.f};
#pragma unroll
    for (int ks = 0; ks < 64; ks += 32) {
        half8v a[4], bfr[6];
#pragma unroll
        for (int mf = 0; mf < 4; ++mf)
            a[mf] = *(const half8v*)&u.st.A[(mt0 + mf * 16 + l16) * 72 + ks + quad * 8];
#pragma unroll
        for (int nf = 0; nf < 6; ++nf)
            bfr[nf] = *(const half8v*)&u.st.B[(nt0 + nf * 16 + l16) * 72 + ks + quad * 8];
#pragma unroll
        for (int mf = 0; mf < 4; ++mf)
#pragma unroll
            for (int nf = 0; nf < 6; ++nf) acc[mf][nf] = MFMA16(a[mf], bfr[nf], acc[mf][nf]);
    }
    __syncthreads();
    const float qscale = 0.17677669529663687f;
#pragma unroll
    for (int mf = 0; mf < 4; ++mf)
#pragma unroll
        for (int nf = 0; nf < 6; ++nf) {
            int j = nt0 + nf * 16 + l16;
            float bias = bias_s[j];
            float sc = (j < 64) ? qscale : 1.f;
#pragma unroll
            for (int r = 0; r < 4; ++r) {
                int tl = mt0 + mf * 16 + quad * 4 + r;
                u.outb[tl * 200 + j] = (_Float16)((acc[mf][nf][r] + bias) * sc);
            }
        }
    __syncthreads();
    for (int i = tid; i < 4096; i += 256) {
        int tk = i >> 5, rem = i & 31;
        if (rem < 24)
            *(half8v*)&qkv16[(size_t)(t0 + tk) * C3 + rem * 8] =
                *(const half8v*)&u.outb[tk * 200 + rem * 8];
    }
}

// ============ K2: attention + proj + residual + LN2 fused. grid 512 (8x8 tile, both heads) ============
// LDS 77.7KB carved: kv(->x2t/stats) | q(->projA) | s(->projB) | rpb. 2 blocks/CU.
__global__ __launch_bounds__(256) void k_attnproj(const _Float16* __restrict__ qkv16,
        const float* __restrict__ rpb,
        const _Float16* __restrict__ pw16, const float* __restrict__ pb,
        const float* __restrict__ x,
        const float* __restrict__ ln2w, const float* __restrict__ ln2b,
        _Float16* __restrict__ x2_16, _Float16* __restrict__ xn2_16) {
    __shared__ __align__(16) char smem[77704];
    _Float16* kv_s  = (_Float16*)smem;              // [196*136] k/v (until PV)
    _Float16* q_s   = (_Float16*)(smem + 53312);    // [64*80] q -> projA [64*72]
    _Float16* s_s   = (_Float16*)(smem + 63552);    // [128*50] scores -> projB [64*72]
    float*    rpb_s = (float*)(smem + 76352);       // [338]
    // post-PV overlays (kv region):
    float* x2t  = (float*)smem;                     // [64*68] = 17408 B
    float* ps1  = (float*)(smem + 20480);           // [256]
    float* ps2  = (float*)(smem + 21504);           // [256]
    float* m_s  = (float*)(smem + 22528);           // [64]
    float* r_s  = (float*)(smem + 22784);           // [64]
    float* w_s  = (float*)(smem + 23040);           // [64]
    float* b_s  = (float*)(smem + 23296);           // [64]
    float* pb_s = (float*)(smem + 23552);           // [64]

    int tid = threadIdx.x;
    int bx = blockIdx.x;
    int n  = bx >> 8;
    int th = (bx >> 4) & 15, tw = bx & 15;
    int h0 = th * 8, w0 = tw * 8;
    int wr0 = min(max(h0 - 3, 0), HH - 14);
    int ww0 = min(max(w0 - 3, 0), WW - 14);
    int tbase = n << 14;
    int lane = tid & 63, wvi = tid >> 6;
    int quad = lane >> 4, l16 = lane & 15;

    for (int i = tid; i < 338; i += 256) rpb_s[i] = rpb[i];
    for (int i = tid; i < 196 * 16; i += 256) {
        int tok = i >> 4, u = i & 15;
        int wi = tok / 14, wj = tok - wi * 14;
        *(half8v*)&kv_s[tok * 136 + u * 8] = *(const half8v*)&qkv16[
            (size_t)(tbase + (wr0 + wi) * WW + ww0 + wj) * C3 + 64 + u * 8];
    }
    for (int i = tid; i < 64 * 8; i += 256) {
        int q = i >> 3, u = i & 7;
        int qg = tbase + (h0 + (q >> 3)) * WW + (w0 + (q & 7));
        *(half8v*)&q_s[q * 80 + u * 8] = *(const half8v*)&qkv16[(size_t)qg * C3 + u * 8];
    }
    __syncthreads();

    int c16 = tid & 1, z = (tid >> 1) & 1, q = tid >> 2;
    int qy = q >> 3, qx = q & 7;
    int h = h0 + qy, wc = w0 + qx;
    int sh = min(max(h - 3, 0), HH - KS);
    int sw = min(max(wc - 3, 0), WW - KS);
    int oh = sh - wr0, ow = sw - ww0;
    int dhp = h - sh + 6, dwp = wc - sw + 6;
    {
        const half8v* qp = (const half8v*)&q_s[q * 80 + z * 32];
        half8v q0 = qp[0], q1 = qp[1], q2 = qp[2], q3 = qp[3];
        int i7 = 0, j7 = c16;
        for (int nb = c16; nb < 49; nb += 2) {
            int tok = (oh + i7) * 14 + (ow + j7);
            const half8v* kp = (const half8v*)&kv_s[tok * 136 + z * 32];
            half2v acc2 = { (_Float16)0.f, (_Float16)0.f };
            half8v k0 = kp[0], k1 = kp[1], k2 = kp[2], k3 = kp[3];
            acc2 += (half2v){k0.s0, k0.s1} * (half2v){q0.s0, q0.s1};
            acc2 += (half2v){k0.s2, k0.s3} * (half2v){q0.s2, q0.s3};
            acc2 += (half2v){k0.s4, k0.s5} * (half2v){q0.s4, q0.s5};
            acc2 += (half2v){k0.s6, k0.s7} * (half2v){q0.s6, q0.s7};
            acc2 += (half2v){k1.s0, k1.s1} * (half2v){q1.s0, q1.s1};
            acc2 += (half2v){k1.s2, k1.s3} * (half2v){q1.s2, q1.s3};
            acc2 += (half2v){k1.s4, k1.s5} * (half2v){q1.s4, q1.s5};
            acc2 += (half2v){k1.s6, k1.s7} * (half2v){q1.s6, q1.s7};
            acc2 += (half2v){k2.s0, k2.s1} * (half2v){q2.s0, q2.s1};
            acc2 += (half2v){k2.s2, k2.s3} * (half2v){q2.s2, q2.s3};
            acc2 += (half2v){k2.s4, k2.s5} * (half2v){q2.s4, q2.s5};
            acc2 += (half2v){k2.s6, k2.s7} * (half2v){q2.s6, q2.s7};
            acc2 += (half2v){k3.s0, k3.s1} * (half2v){q3.s0, q3.s1};
            acc2 += (half2v){k3.s2, k3.s3} * (half2v){q3.s2, q3.s3};
            acc2 += (half2v){k3.s4, k3.s5} * (half2v){q3.s4, q3.s5};
            acc2 += (half2v){k3.s6, k3.s7} * (half2v){q3.s6, q3.s7};
            float s = (float)acc2.x + (float)acc2.y
                    + rpb_s[(z * 13 + (dhp - i7)) * 13 + (dwp - j7)];
            s_s[(q * 2 + z) * 50 + nb] = (_Float16)s;
            j7 += 2;
            if (j7 >= 7) { j7 -= 7; ++i7; }
        }
    }
    __syncthreads();

    if (tid < 128) {
        _Float16* sp = &s_s[tid * 50];
        float mx = -1e30f;
        for (int i = 0; i < 49; ++i) mx = fmaxf(mx, (float)sp[i]);
        float sum = 0.f;
        for (int i = 0; i < 49; ++i) {
            float e = __expf((float)sp[i] - mx);
            sum += e;
            sp[i] = (_Float16)e;
        }
        float inv = 1.f / sum;
        for (int i = 0; i < 49; ++i) sp[i] = (_Float16)((float)sp[i] * inv);
    }
    __syncthreads();

    // ---- PV -> attn out written to q_s region (proj A-operand, stride 72) ----
    {
        const _Float16* pp = &s_s[(q * 2 + z) * 50];
        half2v acc[8];
#pragma unroll
        for (int j = 0; j < 8; ++j) acc[j] = (half2v){ (_Float16)0.f, (_Float16)0.f };
        int i7 = 0, j7 = 0;
        for (int nb = 0; nb < 49; ++nb) {
            int tok = (oh + i7) * 14 + (ow + j7);
            _Float16 p = pp[nb];
            half2v p2 = { p, p };
            const half8v* vp = (const half8v*)&kv_s[tok * 136 + 64 + z * 32 + c16 * 16];
            half8v v0 = vp[0], v1 = vp[1];
            acc[0] += (half2v){v0.s0, v0.s1} * p2;
            acc[1] += (half2v){v0.s2, v0.s3} * p2;
            acc[2] += (half2v){v0.s4, v0.s5} * p2;
            acc[3] += (half2v){v0.s6, v0.s7} * p2;
            acc[4] += (half2v){v1.s0, v1.s1} * p2;
            acc[5] += (half2v){v1.s2, v1.s3} * p2;
            acc[6] += (half2v){v1.s4, v1.s5} * p2;
            acc[7] += (half2v){v1.s6, v1.s7} * p2;
            ++j7;
            if (j7 == 7) { j7 = 0; ++i7; }
        }
        _Float16* op = q_s + q * 72 + z * 32 + c16 * 16;
        half8v o0 = {acc[0].x, acc[0].y, acc[1].x, acc[1].y, acc[2].x, acc[2].y, acc[3].x, acc[3].y};
        half8v o1 = {acc[4].x, acc[4].y, acc[5].x, acc[5].y, acc[6].x, acc[6].y, acc[7].x, acc[7].y};
        *(half8v*)op = o0;
        *(half8v*)(op + 8) = o1;
    }
    __syncthreads();   // PV reads of s_s/kv_s complete; outA complete
    // ---- stage proj B (pre-converted f16) + LN params ----
    for (int i = tid; i < 512; i += 256) {
        int jj = i >> 3, c8 = i & 7;
        *(half8v*)&s_s[jj * 72 + c8 * 8] = *(const half8v*)&pw16[jj * 64 + c8 * 8];
    }
    if (tid < 64) { w_s[tid] = ln2w[tid]; b_s[tid] = ln2b[tid]; pb_s[tid] = pb[tid]; }
    __syncthreads();
    // ---- proj GEMM: 4 waves x (16t x 64j), K=64 ----
    {
        int mt0 = wvi * 16;
        f32x4 acc2[4];
#pragma unroll
        for (int nf = 0; nf < 4; ++nf) acc2[nf] = (f32x4){0.f, 0.f, 0.f, 0.f};
#pragma unroll
        for (int ks = 0; ks < 64; ks += 32) {
            half8v a = *(const half8v*)&q_s[(mt0 + l16) * 72 + ks + quad * 8];
            half8v bfr[4];
#pragma unroll
            for (int nf = 0; nf < 4; ++nf)
                bfr[nf] = *(const half8v*)&s_s[(nf * 16 + l16) * 72 + ks + quad * 8];
#pragma unroll
            for (int nf = 0; nf < 4; ++nf) acc2[nf] = MFMA16(a, bfr[nf], acc2[nf]);
        }
        __syncthreads();   // A/B reads done before x2t (kv region) overwrite
        int tl0 = mt0 + quad * 4;
        int hwl = (h0 + (tl0 >> 3)) * WW + w0 + (tl0 & 7);
#pragma unroll
        for (int nf = 0; nf < 4; ++nf) {
            int j = nf * 16 + l16;
            float bias = pb_s[j];
            float4 rx = *(const float4*)&x[((size_t)(n * CC + j) << 14) + hwl];
#pragma unroll
            for (int r = 0; r < 4; ++r)
                x2t[(tl0 + r) * 68 + j] = acc2[nf][r] + bias + ((const float*)&rx)[r];
        }
    }
    __syncthreads();
    // ---- LN2: stats + dual write (spatial token mapping) ----
    int tok = tid & 63, cq = tid >> 6;
    {
        float s = 0.f, s2 = 0.f;
#pragma unroll
        for (int e = 0; e < 16; ++e) {
            float f = x2t[tok * 68 + cq * 16 + e];
            s += f; s2 += f * f;
        }
        ps1[tid] = s; ps2[tid] = s2;
    }
    __syncthreads();
    if (tid < 64) {
        float ss = ps1[tid] + ps1[64 + tid] + ps1[128 + tid] + ps1[192 + tid];
        float qq = ps2[tid] + ps2[64 + tid] + ps2[128 + tid] + ps2[192 + tid];
        float m = ss * (1.f / 64.f);
        float var = qq * (1.f / 64.f) - m * m;
        m_s[tid] = m; r_s[tid] = rsqrtf(var + 1e-5f);
    }
    __syncthreads();
    {
        float m = m_s[tok], r = r_s[tok];
        int qg = tbase + (h0 + (tok >> 3)) * WW + (w0 + (tok & 7));
        half8v hv0, hv1, nv0, nv1;
#pragma unroll
        for (int e = 0; e < 8; ++e) {
            int c = cq * 16 + e;
            float f = x2t[tok * 68 + c];
            hv0[e] = (_Float16)f;
            nv0[e] = (_Float16)((f - m) * r * w_s[c] + b_s[c]);
        }
#pragma unroll
        for (int e = 0; e < 8; ++e) {
            int c = cq * 16 + 8 + e;
            float f = x2t[tok * 68 + c];
            hv1[e] = (_Float16)f;
            nv1[e] = (_Float16)((f - m) * r * w_s[c] + b_s[c]);
        }
        size_t base = (size_t)qg * 64 + cq * 16;
        *(half8v*)&x2_16[base] = hv0;  *(half8v*)&x2_16[base + 8] = hv1;
        *(half8v*)&xn2_16[base] = nv0; *(half8v*)&xn2_16[base + 8] = nv1;
    }
}

// ============ K3: fused MLP (fc1+GELU+fc2+residual+NCHW out), f16 weight staging. grid 512 ============
__global__ __launch_bounds__(256) void k_mlp(const _Float16* __restrict__ xn2,
        const _Float16* __restrict__ x2_16,
        const _Float16* __restrict__ f1w16, const float* __restrict__ f1b,
        const _Float16* __restrict__ f2w16, const float* __restrict__ f2b,
        float* __restrict__ out) {
    __shared__ __align__(16) _Float16 H_s[64 * 264];
    __shared__ union {
        struct { __align__(16) _Float16 A[64 * 72]; __align__(16) _Float16 B[128 * 72]; } st;
        float tr[64 * 68];
    } u;
    __shared__ float f1b_s[256], f2b_s[64];
    int tid = threadIdx.x;
    int t0 = blockIdx.x * 64;
    int lane = tid & 63, wv = tid >> 6;
    int quad = lane >> 4, l16 = lane & 15;
    f1b_s[tid] = f1b[tid];
    if (tid < 64) f2b_s[tid] = f2b[tid];
    for (int i = tid; i < 512; i += 256) {
        int tok = i >> 3, u8 = i & 7;
        *(half8v*)&u.st.A[tok * 72 + u8 * 8] = *(const half8v*)&xn2[(size_t)(t0 + tok) * 64 + u8 * 8];
    }
    for (int jh = 0; jh < 2; ++jh) {
        if (jh) __syncthreads();
        for (int i = tid; i < 1024; i += 256) {
            int jj = i >> 3, c8 = i & 7;
            *(half8v*)&u.st.B[jj * 72 + c8 * 8] =
                *(const half8v*)&f1w16[(size_t)(jh * 128 + jj) * 64 + c8 * 8];
        }
        __syncthreads();
        int mt0 = (wv & 1) * 32, nt0 = (wv >> 1) * 64;
        f32x4 acc[2][4];
#pragma unroll
        for (int mf = 0; mf < 2; ++mf)
#pragma unroll
            for (int nf = 0; nf < 4; ++nf) acc[mf][nf] = (f32x4){0.f, 0.f, 0.f, 0.f};
#pragma unroll
        for (int ks = 0; ks < 64; ks += 32) {
            half8v a[2], bfr[4];
#pragma unroll
            for (int mf = 0; mf < 2; ++mf)
                a[mf] = *(const half8v*)&u.st.A[(mt0 + mf * 16 + l16) * 72 + ks + quad * 8];
#pragma unroll
            for (int nf = 0; nf < 4; ++nf)
                bfr[nf] = *(const half8v*)&u.st.B[(nt0 + nf * 16 + l16) * 72 + ks + quad * 8];
#pragma unroll
            for (int mf = 0; mf < 2; ++mf)
#pragma unroll
                for (int nf = 0; nf < 4; ++nf) acc[mf][nf] = MFMA16(a[mf], bfr[nf], acc[mf][nf]);
        }
#pragma unroll
        for (int mf = 0; mf < 2; ++mf)
#pragma unroll
            for (int nf = 0; nf < 4; ++nf) {
                int jl = nt0 + nf * 16 + l16;
                float bias = f1b_s[jh * 128 + jl];
#pragma unroll
                for (int r = 0; r < 4; ++r) {
                    int tl = mt0 + mf * 16 + quad * 4 + r;
                    float vv = acc[mf][nf][r] + bias;
                    float g = 0.5f * vv * (1.f + erff(vv * 0.70710678118654752f));
                    H_s[tl * 264 + jh * 128 + jl] = (_Float16)g;
                }
            }
    }
    __syncthreads();
    int mt0 = wv * 16;
    f32x4 acc2[4];
#pragma unroll
    for (int nf = 0; nf < 4; ++nf) acc2[nf] = (f32x4){0.f, 0.f, 0.f, 0.f};
    for (int kp = 0; kp < 4; ++kp) {
        if (kp) __syncthreads();
        for (int i = tid; i < 512; i += 256) {
            int jj = i >> 3, c8 = i & 7;
            *(half8v*)&u.st.B[jj * 72 + c8 * 8] =
                *(const half8v*)&f2w16[(size_t)jj * C4 + kp * 64 + c8 * 8];
        }
        __syncthreads();
#pragma unroll
        for (int ks = 0; ks < 64; ks += 32) {
            half8v a = *(const half8v*)&H_s[(mt0 + l16) * 264 + kp * 64 + ks + quad * 8];
            half8v bfr[4];
#pragma unroll
            for (int nf = 0; nf < 4; ++nf)
                bfr[nf] = *(const half8v*)&u.st.B[(nf * 16 + l16) * 72 + ks + quad * 8];
#pragma unroll
            for (int nf = 0; nf < 4; ++nf) acc2[nf] = MFMA16(a, bfr[nf], acc2[nf]);
        }
    }
    __syncthreads();
#pragma unroll
    for (int nf = 0; nf < 4; ++nf) {
        int j = nf * 16 + l16;
        float bias = f2b_s[j];
#pragma unroll
        for (int r = 0; r < 4; ++r) {
            int tl = mt0 + quad * 4 + r;
            float v = acc2[nf][r] + bias + (float)x2_16[(size_t)(t0 + tl) * 64 + j];
            u.tr[j * 68 + tl] = v;
        }
    }
    __syncthreads();
    int n = t0 >> 14, hw0 = t0 & (HWSZ - 1);
    for (int i = tid; i < 1024; i += 256) {
        int j = i >> 4, seg = i & 15;
        float4 v = *(const float4*)&u.tr[j * 68 + seg * 4];
        *(float4*)&out[((size_t)(n * CC + j) << 14) + hw0 + seg * 4] = v;
    }
}

extern "C" void kernel_launch(void* const* d_in, const int* in_sizes, int n_in,
                              void* d_out, int out_size, void* d_ws, size_t ws_size,
                              hipStream_t stream) {
    const float* x      = (const float*)d_in[0];
    const float* qkv_w  = (const float*)d_in[1];
    const float* qkv_b  = (const float*)d_in[2];
    const float* proj_w = (const float*)d_in[3];
    const float* proj_b = (const float*)d_in[4];
    const float* rpb    = (const float*)d_in[5];
    const float* ln1_w  = (const float*)d_in[6];
    const float* ln1_b  = (const float*)d_in[7];
    const float* ln2_w  = (const float*)d_in[8];
    const float* ln2_b  = (const float*)d_in[9];
    const float* fc1_w  = (const float*)d_in[10];
    const float* fc1_b  = (const float*)d_in[11];
    const float* fc2_w  = (const float*)d_in[12];
    const float* fc2_b  = (const float*)d_in[13];
    float* out = (float*)d_out;
    char* ws = (char*)d_ws;

    _Float16* qkv16  = (_Float16*)(ws);                 // 12.58 MB [T][192]
    _Float16* x2_16  = (_Float16*)(ws + 12582912);      //  4.19 MB [T][64]
    _Float16* xn2_16 = (_Float16*)(ws + 16777216);      //  4.19 MB [T][64]
    _Float16* pw16   = (_Float16*)(ws + 20971520);      //  8 KB
    _Float16* f1w16  = (_Float16*)(ws + 20979712);      // 32 KB
    _Float16* f2w16  = (_Float16*)(ws + 21012480);      // 32 KB

    k_qkvln   <<<256, 256, 0, stream>>>(x, ln1_w, ln1_b, qkv_w, qkv_b,
                                        proj_w, fc1_w, fc2_w,
                                        qkv16, pw16, f1w16, f2w16);
    k_attnproj<<<512, 256, 0, stream>>>(qkv16, rpb, pw16, proj_b, x, ln2_w, ln2_b,
                                        x2_16, xn2_16);
    k_mlp     <<<512, 256, 0, stream>>>(xn2_16, x2_16, f1w16, fc1_b, f2w16, fc2_b, out);
}

// Round 12
// 128.482 us; speedup vs baseline: 1.3056x; 1.0318x over previous
//
#include <hip/hip_runtime.h>
#include <math.h>

#define TQ   32768
#define HWSZ 16384
#define CC   64
#define HH   128
#define WW   128
#define C3   192
#define C4   256
#define KS   7

typedef _Float16 half2v __attribute__((ext_vector_type(2)));
typedef _Float16 half4v __attribute__((ext_vector_type(4)));
typedef _Float16 half8v __attribute__((ext_vector_type(8)));
typedef float    f32x4  __attribute__((ext_vector_type(4)));

#define MFMA16(a, b, c) __builtin_amdgcn_mfma_f32_16x16x32_f16((a), (b), (c), 0, 0, 0)

// ============ K1: LN1 + QKV GEMM + weight-f16 preconvert tail. grid 256 (R11) ============
__global__ __launch_bounds__(256) void k_qkvln(const float* __restrict__ x,
        const float* __restrict__ lnw, const float* __restrict__ lnb,
        const float* __restrict__ qw, const float* __restrict__ qb,
        const float* __restrict__ pw, const float* __restrict__ f1w,
        const float* __restrict__ f2w,
        _Float16* __restrict__ qkv16, _Float16* __restrict__ pw16,
        _Float16* __restrict__ f1w16, _Float16* __restrict__ f2w16) {
    __shared__ union {
        struct { __align__(16) _Float16 A[128 * 72]; __align__(16) _Float16 B[192 * 72]; } st;
        __align__(16) _Float16 outb[128 * 200];
    } u;
    __shared__ float ps1[256], ps2[256], m_s[128], r_s[128];
    __shared__ float w_s[64], b_s[64], bias_s[192];
    int tid = threadIdx.x;
    int t0 = blockIdx.x * 128;
    if (tid < 64) { w_s[tid] = lnw[tid]; b_s[tid] = lnb[tid]; }
    if (tid < 192) bias_s[tid] = qb[tid];
    int tok = tid & 127, cq = tid >> 7;
    int t = t0 + tok;
    int n = t >> 14, hw = t & (HWSZ - 1);
    const float* xr = x + ((size_t)n << 20) + hw;
    float v[32];
    float s = 0.f, s2 = 0.f;
#pragma unroll
    for (int e = 0; e < 32; ++e) {
        float f = xr[(cq * 32 + e) * HWSZ];
        v[e] = f; s += f; s2 += f * f;
    }
    ps1[tid] = s; ps2[tid] = s2;
    for (int i = tid; i < 3072; i += 256) {
        int jj = i >> 4, seg = i & 15;
        float4 v4 = *(const float4*)&qw[(size_t)jj * 64 + seg * 4];
        half4v h4 = { (_Float16)v4.x, (_Float16)v4.y, (_Float16)v4.z, (_Float16)v4.w };
        *(half4v*)&u.st.B[jj * 72 + seg * 4] = h4;
    }
    {
        int g = blockIdx.x * 256 + tid;
        if (g < 4096) pw16[g] = (_Float16)pw[g];
        else if (g < 20480) f1w16[g - 4096] = (_Float16)f1w[g - 4096];
        else if (g < 36864) f2w16[g - 20480] = (_Float16)f2w[g - 20480];
    }
    __syncthreads();
    if (tid < 128) {
        float ss = ps1[tid] + ps1[tid + 128];
        float qq = ps2[tid] + ps2[tid + 128];
        float m = ss * (1.f / 64.f);
        float var = qq * (1.f / 64.f) - m * m;
        m_s[tid] = m; r_s[tid] = rsqrtf(var + 1e-5f);
    }
    __syncthreads();
    {
        float m = m_s[tok], r = r_s[tok];
#pragma unroll
        for (int u8 = 0; u8 < 4; ++u8) {
            half8v o;
#pragma unroll
            for (int e = 0; e < 8; ++e) {
                int c = cq * 32 + u8 * 8 + e;
                o[e] = (_Float16)((v[u8 * 8 + e] - m) * r * w_s[c] + b_s[c]);
            }
            *(half8v*)&u.st.A[tok * 72 + cq * 32 + u8 * 8] = o;
        }
    }
    __syncthreads();
    int lane = tid & 63, wv = tid >> 6;
    int quad = lane >> 4, l16 = lane & 15;
    int mt0 = (wv & 1) * 64, nt0 = (wv >> 1) * 96;
    f32x4 acc[4][6];
#pragma unroll
    for (int mf = 0; mf < 4; ++mf)
#pragma unroll
        for (int nf = 0; nf < 6; ++nf) acc[mf][nf] = (f32x4){0.f, 0.f, 0.f, 0.f};
#pragma unroll
    for (int ks = 0; ks < 64; ks += 32) {
        half8v a[4], bfr[6];
#pragma unroll
        for (int mf = 0; mf < 4; ++mf)
            a[mf] = *(const half8v*)&u.st.A[(mt0 + mf * 16 + l16) * 72 + ks + quad * 8];
#pragma unroll
        for (int nf = 0; nf < 6; ++nf)
            bfr[nf] = *(const half8v*)&u.st.B[(nt0 + nf * 16 + l16) * 72 + ks + quad * 8];
#pragma unroll
        for (int mf = 0; mf < 4; ++mf)
#pragma unroll
            for (int nf = 0; nf < 6; ++nf) acc[mf][nf] = MFMA16(a[mf], bfr[nf], acc[mf][nf]);
    }
    __syncthreads();
    const float qscale = 0.17677669529663687f;
#pragma unroll
    for (int mf = 0; mf < 4; ++mf)
#pragma unroll
        for (int nf = 0; nf < 6; ++nf) {
            int j = nt0 + nf * 16 + l16;
            float bias = bias_s[j];
            float sc = (j < 64) ? qscale : 1.f;
#pragma unroll
            for (int r = 0; r < 4; ++r) {
                int tl = mt0 + mf * 16 + quad * 4 + r;
                u.outb[tl * 200 + j] = (_Float16)((acc[mf][nf][r] + bias) * sc);
            }
        }
    __syncthreads();
    for (int i = tid; i < 4096; i += 256) {
        int tk = i >> 5, rem = i & 31;
        if (rem < 24)
            *(half8v*)&qkv16[(size_t)(t0 + tk) * C3 + rem * 8] =
                *(const half8v*)&u.outb[tk * 200 + rem * 8];
    }
}

// ============ K2: attention + proj + residual + LN2 fused. grid 512 (R11, unchanged) ============
__global__ __launch_bounds__(256) void k_attnproj(const _Float16* __restrict__ qkv16,
        const float* __restrict__ rpb,
        const _Float16* __restrict__ pw16, const float* __restrict__ pb,
        const float* __restrict__ x,
        const float* __restrict__ ln2w, const float* __restrict__ ln2b,
        _Float16* __restrict__ x2_16, _Float16* __restrict__ xn2_16) {
    __shared__ __align__(16) char smem[77704];
    _Float16* kv_s  = (_Float16*)smem;
    _Float16* q_s   = (_Float16*)(smem + 53312);
    _Float16* s_s   = (_Float16*)(smem + 63552);
    float*    rpb_s = (float*)(smem + 76352);
    float* x2t  = (float*)smem;
    float* ps1  = (float*)(smem + 20480);
    float* ps2  = (float*)(smem + 21504);
    float* m_s  = (float*)(smem + 22528);
    float* r_s  = (float*)(smem + 22784);
    float* w_s  = (float*)(smem + 23040);
    float* b_s  = (float*)(smem + 23296);
    float* pb_s = (float*)(smem + 23552);

    int tid = threadIdx.x;
    int bx = blockIdx.x;
    int n  = bx >> 8;
    int th = (bx >> 4) & 15, tw = bx & 15;
    int h0 = th * 8, w0 = tw * 8;
    int wr0 = min(max(h0 - 3, 0), HH - 14);
    int ww0 = min(max(w0 - 3, 0), WW - 14);
    int tbase = n << 14;
    int lane = tid & 63, wvi = tid >> 6;
    int quad = lane >> 4, l16 = lane & 15;

    for (int i = tid; i < 338; i += 256) rpb_s[i] = rpb[i];
    for (int i = tid; i < 196 * 16; i += 256) {
        int tok = i >> 4, u = i & 15;
        int wi = tok / 14, wj = tok - wi * 14;
        *(half8v*)&kv_s[tok * 136 + u * 8] = *(const half8v*)&qkv16[
            (size_t)(tbase + (wr0 + wi) * WW + ww0 + wj) * C3 + 64 + u * 8];
    }
    for (int i = tid; i < 64 * 8; i += 256) {
        int q = i >> 3, u = i & 7;
        int qg = tbase + (h0 + (q >> 3)) * WW + (w0 + (q & 7));
        *(half8v*)&q_s[q * 80 + u * 8] = *(const half8v*)&qkv16[(size_t)qg * C3 + u * 8];
    }
    __syncthreads();

    int c16 = tid & 1, z = (tid >> 1) & 1, q = tid >> 2;
    int qy = q >> 3, qx = q & 7;
    int h = h0 + qy, wc = w0 + qx;
    int sh = min(max(h - 3, 0), HH - KS);
    int sw = min(max(wc - 3, 0), WW - KS);
    int oh = sh - wr0, ow = sw - ww0;
    int dhp = h - sh + 6, dwp = wc - sw + 6;
    {
        const half8v* qp = (const half8v*)&q_s[q * 80 + z * 32];
        half8v q0 = qp[0], q1 = qp[1], q2 = qp[2], q3 = qp[3];
        int i7 = 0, j7 = c16;
        for (int nb = c16; nb < 49; nb += 2) {
            int tok = (oh + i7) * 14 + (ow + j7);
            const half8v* kp = (const half8v*)&kv_s[tok * 136 + z * 32];
            half2v acc2 = { (_Float16)0.f, (_Float16)0.f };
            half8v k0 = kp[0], k1 = kp[1], k2 = kp[2], k3 = kp[3];
            acc2 += (half2v){k0.s0, k0.s1} * (half2v){q0.s0, q0.s1};
            acc2 += (half2v){k0.s2, k0.s3} * (half2v){q0.s2, q0.s3};
            acc2 += (half2v){k0.s4, k0.s5} * (half2v){q0.s4, q0.s5};
            acc2 += (half2v){k0.s6, k0.s7} * (half2v){q0.s6, q0.s7};
            acc2 += (half2v){k1.s0, k1.s1} * (half2v){q1.s0, q1.s1};
            acc2 += (half2v){k1.s2, k1.s3} * (half2v){q1.s2, q1.s3};
            acc2 += (half2v){k1.s4, k1.s5} * (half2v){q1.s4, q1.s5};
            acc2 += (half2v){k1.s6, k1.s7} * (half2v){q1.s6, q1.s7};
            acc2 += (half2v){k2.s0, k2.s1} * (half2v){q2.s0, q2.s1};
            acc2 += (half2v){k2.s2, k2.s3} * (half2v){q2.s2, q2.s3};
            acc2 += (half2v){k2.s4, k2.s5} * (half2v){q2.s4, q2.s5};
            acc2 += (half2v){k2.s6, k2.s7} * (half2v){q2.s6, q2.s7};
            acc2 += (half2v){k3.s0, k3.s1} * (half2v){q3.s0, q3.s1};
            acc2 += (half2v){k3.s2, k3.s3} * (half2v){q3.s2, q3.s3};
            acc2 += (half2v){k3.s4, k3.s5} * (half2v){q3.s4, q3.s5};
            acc2 += (half2v){k3.s6, k3.s7} * (half2v){q3.s6, q3.s7};
            float s = (float)acc2.x + (float)acc2.y
                    + rpb_s[(z * 13 + (dhp - i7)) * 13 + (dwp - j7)];
            s_s[(q * 2 + z) * 50 + nb] = (_Float16)s;
            j7 += 2;
            if (j7 >= 7) { j7 -= 7; ++i7; }
        }
    }
    __syncthreads();

    if (tid < 128) {
        _Float16* sp = &s_s[tid * 50];
        float mx = -1e30f;
        for (int i = 0; i < 49; ++i) mx = fmaxf(mx, (float)sp[i]);
        float sum = 0.f;
        for (int i = 0; i < 49; ++i) {
            float e = __expf((float)sp[i] - mx);
            sum += e;
            sp[i] = (_Float16)e;
        }
        float inv = 1.f / sum;
        for (int i = 0; i < 49; ++i) sp[i] = (_Float16)((float)sp[i] * inv);
    }
    __syncthreads();

    {
        const _Float16* pp = &s_s[(q * 2 + z) * 50];
        half2v acc[8];
#pragma unroll
        for (int j = 0; j < 8; ++j) acc[j] = (half2v){ (_Float16)0.f, (_Float16)0.f };
        int i7 = 0, j7 = 0;
        for (int nb = 0; nb < 49; ++nb) {
            int tok = (oh + i7) * 14 + (ow + j7);
            _Float16 p = pp[nb];
            half2v p2 = { p, p };
            const half8v* vp = (const half8v*)&kv_s[tok * 136 + 64 + z * 32 + c16 * 16];
            half8v v0 = vp[0], v1 = vp[1];
            acc[0] += (half2v){v0.s0, v0.s1} * p2;
            acc[1] += (half2v){v0.s2, v0.s3} * p2;
            acc[2] += (half2v){v0.s4, v0.s5} * p2;
            acc[3] += (half2v){v0.s6, v0.s7} * p2;
            acc[4] += (half2v){v1.s0, v1.s1} * p2;
            acc[5] += (half2v){v1.s2, v1.s3} * p2;
            acc[6] += (half2v){v1.s4, v1.s5} * p2;
            acc[7] += (half2v){v1.s6, v1.s7} * p2;
            ++j7;
            if (j7 == 7) { j7 = 0; ++i7; }
        }
        _Float16* op = q_s + q * 72 + z * 32 + c16 * 16;
        half8v o0 = {acc[0].x, acc[0].y, acc[1].x, acc[1].y, acc[2].x, acc[2].y, acc[3].x, acc[3].y};
        half8v o1 = {acc[4].x, acc[4].y, acc[5].x, acc[5].y, acc[6].x, acc[6].y, acc[7].x, acc[7].y};
        *(half8v*)op = o0;
        *(half8v*)(op + 8) = o1;
    }
    __syncthreads();
    for (int i = tid; i < 512; i += 256) {
        int jj = i >> 3, c8 = i & 7;
        *(half8v*)&s_s[jj * 72 + c8 * 8] = *(const half8v*)&pw16[jj * 64 + c8 * 8];
    }
    if (tid < 64) { w_s[tid] = ln2w[tid]; b_s[tid] = ln2b[tid]; pb_s[tid] = pb[tid]; }
    __syncthreads();
    {
        int mt0 = wvi * 16;
        f32x4 acc2[4];
#pragma unroll
        for (int nf = 0; nf < 4; ++nf) acc2[nf] = (f32x4){0.f, 0.f, 0.f, 0.f};
#pragma unroll
        for (int ks = 0; ks < 64; ks += 32) {
            half8v a = *(const half8v*)&q_s[(mt0 + l16) * 72 + ks + quad * 8];
            half8v bfr[4];
#pragma unroll
            for (int nf = 0; nf < 4; ++nf)
                bfr[nf] = *(const half8v*)&s_s[(nf * 16 + l16) * 72 + ks + quad * 8];
#pragma unroll
            for (int nf = 0; nf < 4; ++nf) acc2[nf] = MFMA16(a, bfr[nf], acc2[nf]);
        }
        __syncthreads();
        int tl0 = mt0 + quad * 4;
        int hwl = (h0 + (tl0 >> 3)) * WW + w0 + (tl0 & 7);
#pragma unroll
        for (int nf = 0; nf < 4; ++nf) {
            int j = nf * 16 + l16;
            float bias = pb_s[j];
            float4 rx = *(const float4*)&x[((size_t)(n * CC + j) << 14) + hwl];
#pragma unroll
            for (int r = 0; r < 4; ++r)
                x2t[(tl0 + r) * 68 + j] = acc2[nf][r] + bias + ((const float*)&rx)[r];
        }
    }
    __syncthreads();
    int tok = tid & 63, cq = tid >> 6;
    {
        float s = 0.f, s2 = 0.f;
#pragma unroll
        for (int e = 0; e < 16; ++e) {
            float f = x2t[tok * 68 + cq * 16 + e];
            s += f; s2 += f * f;
        }
        ps1[tid] = s; ps2[tid] = s2;
    }
    __syncthreads();
    if (tid < 64) {
        float ss = ps1[tid] + ps1[64 + tid] + ps1[128 + tid] + ps1[192 + tid];
        float qq = ps2[tid] + ps2[64 + tid] + ps2[128 + tid] + ps2[192 + tid];
        float m = ss * (1.f / 64.f);
        float var = qq * (1.f / 64.f) - m * m;
        m_s[tid] = m; r_s[tid] = rsqrtf(var + 1e-5f);
    }
    __syncthreads();
    {
        float m = m_s[tok], r = r_s[tok];
        int qg = tbase + (h0 + (tok >> 3)) * WW + (w0 + (tok & 7));
        half8v hv0, hv1, nv0, nv1;
#pragma unroll
        for (int e = 0; e < 8; ++e) {
            int c = cq * 16 + e;
            float f = x2t[tok * 68 + c];
            hv0[e] = (_Float16)f;
            nv0[e] = (_Float16)((f - m) * r * w_s[c] + b_s[c]);
        }
#pragma unroll
        for (int e = 0; e < 8; ++e) {
            int c = cq * 16 + 8 + e;
            float f = x2t[tok * 68 + c];
            hv1[e] = (_Float16)f;
            nv1[e] = (_Float16)((f - m) * r * w_s[c] + b_s[c]);
        }
        size_t base = (size_t)qg * 64 + cq * 16;
        *(half8v*)&x2_16[base] = hv0;  *(half8v*)&x2_16[base + 8] = hv1;
        *(half8v*)&xn2_16[base] = nv0; *(half8v*)&xn2_16[base + 8] = nv1;
    }
}

// ============ K3: MLP with LDS-resident weights. grid 256 x 512 threads, 1 block/CU ============
// W1 36.9KB + W2 33.8KB staged ONCE; 2 token-tiles of 64; zero weight restaging.
__global__ __launch_bounds__(512, 1) void k_mlp(const _Float16* __restrict__ xn2,
        const _Float16* __restrict__ x2_16,
        const _Float16* __restrict__ f1w16, const float* __restrict__ f1b,
        const _Float16* __restrict__ f2w16, const float* __restrict__ f2b,
        float* __restrict__ out) {
    __shared__ __align__(16) _Float16 W1[256 * 72];     // fc1 weights [j][k], 36.9 KB
    __shared__ __align__(16) _Float16 W2[64 * 264];     // fc2 weights [j][k], 33.8 KB
    __shared__ __align__(16) _Float16 A_s[64 * 72];     // 9.2 KB
    __shared__ union {
        __align__(16) _Float16 H[64 * 264];             // 33.8 KB
        float tr[64 * 68];                              // 17.4 KB
    } u;
    __shared__ float f1b_s[256], f2b_s[64];
    int tid = threadIdx.x;
    int lane = tid & 63, wv = tid >> 6;                 // 8 waves
    int quad = lane >> 4, l16 = lane & 15;
    // ---- stage all weights once ----
    for (int i = tid; i < 2048; i += 512) {
        int jj = i >> 3, c8 = i & 7;
        *(half8v*)&W1[jj * 72 + c8 * 8] = *(const half8v*)&f1w16[(size_t)jj * 64 + c8 * 8];
    }
    for (int i = tid; i < 2048; i += 512) {
        int jj = i >> 5, c8 = i & 31;
        *(half8v*)&W2[jj * 264 + c8 * 8] = *(const half8v*)&f2w16[(size_t)jj * 256 + c8 * 8];
    }
    if (tid < 256) f1b_s[tid] = f1b[tid];
    else if (tid < 320) f2b_s[tid - 256] = f2b[tid - 256];

    for (int tt = 0; tt < 2; ++tt) {
        int t0 = blockIdx.x * 128 + tt * 64;
        // stage A (xn2 tile): 512 chunks over 512 threads
        {
            int tok = tid >> 3, u8 = tid & 7;
            *(half8v*)&A_s[tok * 72 + u8 * 8] =
                *(const half8v*)&xn2[(size_t)(t0 + tok) * 64 + u8 * 8];
        }
        __syncthreads();   // A (+W on first iter) visible
        // ---- fc1: wave tile 32t x 64j ----
        {
            int mt0 = (wv & 1) * 32, nt0 = (wv >> 1) * 64;
            f32x4 acc[2][4];
#pragma unroll
            for (int mf = 0; mf < 2; ++mf)
#pragma unroll
                for (int nf = 0; nf < 4; ++nf) acc[mf][nf] = (f32x4){0.f, 0.f, 0.f, 0.f};
#pragma unroll
            for (int ks = 0; ks < 64; ks += 32) {
                half8v a[2], bfr[4];
#pragma unroll
                for (int mf = 0; mf < 2; ++mf)
                    a[mf] = *(const half8v*)&A_s[(mt0 + mf * 16 + l16) * 72 + ks + quad * 8];
#pragma unroll
                for (int nf = 0; nf < 4; ++nf)
                    bfr[nf] = *(const half8v*)&W1[(nt0 + nf * 16 + l16) * 72 + ks + quad * 8];
#pragma unroll
                for (int mf = 0; mf < 2; ++mf)
#pragma unroll
                    for (int nf = 0; nf < 4; ++nf) acc[mf][nf] = MFMA16(a[mf], bfr[nf], acc[mf][nf]);
            }
#pragma unroll
            for (int mf = 0; mf < 2; ++mf)
#pragma unroll
                for (int nf = 0; nf < 4; ++nf) {
                    int jl = nt0 + nf * 16 + l16;
                    float bias = f1b_s[jl];
#pragma unroll
                    for (int r = 0; r < 4; ++r) {
                        int tl = mt0 + mf * 16 + quad * 4 + r;
                        float vv = acc[mf][nf][r] + bias;
                        float g = 0.5f * vv * (1.f + erff(vv * 0.70710678118654752f));
                        u.H[tl * 264 + jl] = (_Float16)g;
                    }
                }
        }
        __syncthreads();   // H complete
        // ---- fc2: wave tile 16t x 32j, K=256 ----
        {
            int mt = (wv & 3) * 16, n0 = (wv >> 2) * 32;
            f32x4 acc2[2];
#pragma unroll
            for (int nf = 0; nf < 2; ++nf) acc2[nf] = (f32x4){0.f, 0.f, 0.f, 0.f};
#pragma unroll
            for (int ks = 0; ks < 256; ks += 32) {
                half8v a = *(const half8v*)&u.H[(mt + l16) * 264 + ks + quad * 8];
                half8v bfr[2];
#pragma unroll
                for (int nf = 0; nf < 2; ++nf)
                    bfr[nf] = *(const half8v*)&W2[(n0 + nf * 16 + l16) * 264 + ks + quad * 8];
#pragma unroll
                for (int nf = 0; nf < 2; ++nf) acc2[nf] = MFMA16(a, bfr[nf], acc2[nf]);
            }
            __syncthreads();   // all H reads done -> tr overwrite safe
#pragma unroll
            for (int nf = 0; nf < 2; ++nf) {
                int j = n0 + nf * 16 + l16;
                float bias = f2b_s[j];
#pragma unroll
                for (int r = 0; r < 4; ++r) {
                    int tl = mt + quad * 4 + r;
                    float v = acc2[nf][r] + bias + (float)x2_16[(size_t)(t0 + tl) * 64 + j];
                    u.tr[j * 68 + tl] = v;
                }
            }
        }
        __syncthreads();   // tr complete
        // ---- NCHW stores ----
        {
            int n = t0 >> 14, hw0 = t0 & (HWSZ - 1);
            for (int i = tid; i < 1024; i += 512) {
                int j = i >> 4, seg = i & 15;
                float4 v = *(const float4*)&u.tr[j * 68 + seg * 4];
                *(float4*)&out[((size_t)(n * CC + j) << 14) + hw0 + seg * 4] = v;
            }
        }
        __syncthreads();   // tr reads done before next tile's H overwrite
    }
}

extern "C" void kernel_launch(void* const* d_in, const int* in_sizes, int n_in,
                              void* d_out, int out_size, void* d_ws, size_t ws_size,
                              hipStream_t stream) {
    const float* x      = (const float*)d_in[0];
    const float* qkv_w  = (const float*)d_in[1];
    const float* qkv_b  = (const float*)d_in[2];
    const float* proj_w = (const float*)d_in[3];
    const float* proj_b = (const float*)d_in[4];
    const float* rpb    = (const float*)d_in[5];
    const float* ln1_w  = (const float*)d_in[6];
    const float* ln1_b  = (const float*)d_in[7];
    const float* ln2_w  = (const float*)d_in[8];
    const float* ln2_b  = (const float*)d_in[9];
    const float* fc1_w  = (const float*)d_in[10];
    const float* fc1_b  = (const float*)d_in[11];
    const float* fc2_w  = (const float*)d_in[12];
    const float* fc2_b  = (const float*)d_in[13];
    float* out = (float*)d_out;
    char* ws = (char*)d_ws;

    _Float16* qkv16  = (_Float16*)(ws);                 // 12.58 MB [T][192]
    _Float16* x2_16  = (_Float16*)(ws + 12582912);      //  4.19 MB [T][64]
    _Float16* xn2_16 = (_Float16*)(ws + 16777216);      //  4.19 MB [T][64]
    _Float16* pw16   = (_Float16*)(ws + 20971520);      //  8 KB
    _Float16* f1w16  = (_Float16*)(ws + 20979712);      // 32 KB
    _Float16* f2w16  = (_Float16*)(ws + 21012480);      // 32 KB

    k_qkvln   <<<256, 256, 0, stream>>>(x, ln1_w, ln1_b, qkv_w, qkv_b,
                                        proj_w, fc1_w, fc2_w,
                                        qkv16, pw16, f1w16, f2w16);
    k_attnproj<<<512, 256, 0, stream>>>(qkv16, rpb, pw16, proj_b, x, ln2_w, ln2_b,
                                        x2_16, xn2_16);
    k_mlp     <<<256, 512, 0, stream>>>(xn2_16, x2_16, f1w16, fc1_b, f2w16, fc2_b, out);
}